// Round 10
// baseline (663.080 us; speedup 1.0000x reference)
//
#include <hip/hip_runtime.h>
#include <stdint.h>

#define NU 200000
#define NM 100000
#define DIM 64
#define CHK 50000        // gather/transform chunk rows (agg buffer size)
#define SCAN_CHUNK 2048
#define MBK2 64          // buckets per direction
#define SP_M 1563        // movie node span per bucket (ceil(NM/64))
#define SP_U 3125        // user  node span per bucket (NU/64)
#define G_SC 1024        // blocks for count/pair_scatter (fixed chunk assignment)

typedef unsigned short ushort_t;

// ---------------------------------------------------------------------------
// bf16 helpers (RNE)
__device__ __forceinline__ unsigned pack_bf2(float lo, float hi) {
    unsigned ul = __float_as_uint(lo); ul += 0x7fffu + ((ul >> 16) & 1u);
    unsigned uh = __float_as_uint(hi); uh += 0x7fffu + ((uh >> 16) & 1u);
    return (ul >> 16) | (uh & 0xffff0000u);
}
__device__ __forceinline__ float bf_lo(unsigned u) { return __uint_as_float(u << 16); }
__device__ __forceinline__ float bf_hi(unsigned u) { return __uint_as_float(u & 0xffff0000u); }

// ---------------------------------------------------------------------------
// Detect whether edge index arrays are int64 or int32.
__global__ void detect_idx_kernel(const unsigned int* __restrict__ words,
                                  int* __restrict__ flag) {
    __shared__ int nz;
    if (threadIdx.x == 0) nz = 0;
    __syncthreads();
    for (int i = threadIdx.x; i < 2048; i += blockDim.x)
        if (words[2 * i + 1] != 0u) nz = 1;
    __syncthreads();
    if (threadIdx.x == 0) *flag = (nz == 0) ? 1 : 0;   // 1 => int64
}

__device__ __forceinline__ int load_idx(const void* __restrict__ p, int e, int is64) {
    if (is64) return (int)((const long long*)p)[e];
    return ((const int*)p)[e];
}

// ---------------------------------------------------------------------------
// fp32 -> bf16 conversion (RNE), vectorized: float4 in, uint2 out.
__global__ void f32_to_bf16_kernel(const float4* __restrict__ in,
                                   uint2* __restrict__ out, int n4) {
    const int stride = gridDim.x * blockDim.x;
    for (int i = blockIdx.x * blockDim.x + threadIdx.x; i < n4; i += stride) {
        const float4 v = in[i];
        out[i] = make_uint2(pack_bf2(v.x, v.y), pack_bf2(v.z, v.w));
    }
}

// ---------------------------------------------------------------------------
// Per-block 64-bucket histograms, both directions (bucket-major layout
// hist[b*G_SC + blk]); FIXED per-block edge chunks.
__global__ void count_kernel(const void* __restrict__ es, const void* __restrict__ ed,
                             const int* __restrict__ flag,
                             int* __restrict__ hist_m, int* __restrict__ hist_u,
                             int nE, int cpb) {
    __shared__ int h[2 * MBK2];
    if (threadIdx.x < 2 * MBK2) h[threadIdx.x] = 0;
    __syncthreads();
    const int is64 = *flag;
    const int e0 = blockIdx.x * cpb;
    const int e1 = min(nE, e0 + cpb);
    for (int e = e0 + threadIdx.x; e < e1; e += blockDim.x) {
        int s = load_idx(es, e, is64);
        int d = load_idx(ed, e, is64);
        atomicAdd(&h[(unsigned)d / SP_M], 1);
        atomicAdd(&h[MBK2 + (unsigned)s / SP_U], 1);
    }
    __syncthreads();
    if (threadIdx.x < MBK2)
        hist_m[threadIdx.x * G_SC + blockIdx.x] = h[threadIdx.x];
    else if (threadIdx.x < 2 * MBK2)
        hist_u[(threadIdx.x - MBK2) * G_SC + blockIdx.x] = h[threadIdx.x];
}

// ---------------------------------------------------------------------------
// Exclusive scan over n ints, 3 phases (chunk = 2048 = 256 thr x 8).
__global__ void scan_block_sums(const int* __restrict__ a, int* __restrict__ bsum, int n) {
    int base = blockIdx.x * SCAN_CHUNK + threadIdx.x * 8;
    int tot = 0;
#pragma unroll
    for (int k = 0; k < 8; ++k) { int i = base + k; if (i < n) tot += a[i]; }
    __shared__ int sc[256];
    sc[threadIdx.x] = tot;
    __syncthreads();
    for (int off = 128; off > 0; off >>= 1) {
        if (threadIdx.x < off) sc[threadIdx.x] += sc[threadIdx.x + off];
        __syncthreads();
    }
    if (threadIdx.x == 0) bsum[blockIdx.x] = sc[0];
}

__global__ void scan_bsum(int* __restrict__ bsum, int nb) {
    if (blockIdx.x == 0 && threadIdx.x == 0) {
        int acc = 0;
        for (int i = 0; i < nb; ++i) { int v = bsum[i]; bsum[i] = acc; acc += v; }
    }
}

__global__ void scan_apply(int* __restrict__ a, const int* __restrict__ bsum, int n, int nE) {
    const int t = threadIdx.x;
    int base = blockIdx.x * SCAN_CHUNK + t * 8;
    int v[8];
    int tot = 0;
#pragma unroll
    for (int k = 0; k < 8; ++k) { int i = base + k; v[k] = (i < n) ? a[i] : 0; tot += v[k]; }
    __shared__ int sc[256];
    sc[t] = tot;
    __syncthreads();
    for (int off = 1; off < 256; off <<= 1) {
        int x = (t >= off) ? sc[t - off] : 0;
        __syncthreads();
        sc[t] += x;
        __syncthreads();
    }
    int excl = bsum[blockIdx.x] + sc[t] - tot;
#pragma unroll
    for (int k = 0; k < 8; ++k) { int i = base + k; if (i < n) a[i] = excl; excl += v[k]; }
    if (blockIdx.x == 0 && t == 0) a[n] = nE;
}

// ---------------------------------------------------------------------------
// Exclusive scan of per-block bucket histogram (64*G_SC, bucket-major) in
// place; emits bounds[0..64]. 2 blocks (movie, user).
__global__ __launch_bounds__(1024) void
hist_scan_kernel(int* __restrict__ hist_m, int* __restrict__ hist_u,
                 int* __restrict__ bounds_m, int* __restrict__ bounds_u, int nE) {
    int* hist   = (blockIdx.x == 0) ? hist_m : hist_u;
    int* bounds = (blockIdx.x == 0) ? bounds_m : bounds_u;
    const int t = threadIdx.x;          // 1024 threads x 64 = 64*G_SC
    const int base = t * 64;
    int v[64];
    int tot = 0;
#pragma unroll
    for (int k = 0; k < 64; ++k) { v[k] = hist[base + k]; tot += v[k]; }
    __shared__ int sc[1024];
    sc[t] = tot;
    __syncthreads();
    for (int off = 1; off < 1024; off <<= 1) {
        int x = (t >= off) ? sc[t - off] : 0;
        __syncthreads();
        sc[t] += x;
        __syncthreads();
    }
    int excl = sc[t] - tot;
#pragma unroll
    for (int k = 0; k < 64; ++k) { int tmp = v[k]; hist[base + k] = excl; excl += tmp; }
    __syncthreads();
    if (t < MBK2) bounds[t] = hist[t * G_SC];
    else if (t == MBK2) bounds[MBK2] = nE;
}

// ---------------------------------------------------------------------------
// Level-1 scatter, deterministic (LDS cursors, exclusive per-bucket chunks).
__global__ void pair_scatter_kernel(const void* __restrict__ es,
                                    const void* __restrict__ ed,
                                    const int* __restrict__ flag,
                                    const int* __restrict__ hist_m,
                                    const int* __restrict__ hist_u,
                                    unsigned* __restrict__ pr_m,
                                    unsigned* __restrict__ pr_u,
                                    int nE, int cpb) {
    __shared__ int cur[2 * MBK2];
    if (threadIdx.x < MBK2)
        cur[threadIdx.x] = hist_m[threadIdx.x * G_SC + blockIdx.x];
    else if (threadIdx.x < 2 * MBK2)
        cur[threadIdx.x] = hist_u[(threadIdx.x - MBK2) * G_SC + blockIdx.x];
    __syncthreads();
    const int is64 = *flag;
    const int e0 = blockIdx.x * cpb;
    const int e1 = min(nE, e0 + cpb);
    for (int e = e0 + threadIdx.x; e < e1; e += blockDim.x) {
        const int s = load_idx(es, e, is64);
        const int d = load_idx(ed, e, is64);
        const int b0 = (unsigned)d / SP_M;
        const int b1 = (unsigned)s / SP_U;
        const int p0 = atomicAdd(&cur[b0], 1);
        pr_m[p0] = ((unsigned)(d - b0 * SP_M) << 18) | (unsigned)s;
        const int p1 = atomicAdd(&cur[MBK2 + b1], 1);
        pr_u[p1] = ((unsigned)(s - b1 * SP_U) << 17) | (unsigned)d;
    }
}

// ---------------------------------------------------------------------------
// Per-bucket degree count from the pair arrays (LDS hist, coalesced writes).
__global__ __launch_bounds__(1024) void
deg_count_kernel(const unsigned* __restrict__ pr_m, const unsigned* __restrict__ pr_u,
                 const int* __restrict__ bounds_m, const int* __restrict__ bounds_u,
                 int* __restrict__ rp_m, int* __restrict__ rp_u) {
    __shared__ int h[SP_U];
    const int b = blockIdx.x;
    const bool mv = (b < MBK2);
    const int bb = mv ? b : b - MBK2;
    const int span  = mv ? SP_M : SP_U;
    const int shift = mv ? 18 : 17;
    const unsigned* pr = mv ? pr_m : pr_u;
    const int* bounds  = mv ? bounds_m : bounds_u;
    int* rp = mv ? rp_m : rp_u;
    const int n_tot = mv ? NM : NU;
    const int s0 = bounds[bb], s1 = bounds[bb + 1];
    for (int i = threadIdx.x; i < span; i += blockDim.x) h[i] = 0;
    __syncthreads();
    for (int i = s0 + threadIdx.x; i < s1; i += blockDim.x)
        atomicAdd(&h[pr[i] >> shift], 1);
    __syncthreads();
    const int nb = bb * span;
    for (int i = threadIdx.x; i < span && nb + i < n_tot; i += blockDim.x)
        rp[nb + i] = h[i];
}

// ---------------------------------------------------------------------------
// Level-2 fill: ONE block per bucket -> XCD-exclusive adj write regions.
__global__ __launch_bounds__(1024) void
bucket_fill_kernel(const unsigned* __restrict__ pr_m, const unsigned* __restrict__ pr_u,
                   const int* __restrict__ bounds_m, const int* __restrict__ bounds_u,
                   const int* __restrict__ rp_m, const int* __restrict__ rp_u,
                   int* __restrict__ adj_m, int* __restrict__ adj_u) {
    __shared__ int cur[SP_U];
    const int b = blockIdx.x;
    const bool mv = (b < MBK2);
    const int bb = mv ? b : b - MBK2;
    const int span  = mv ? SP_M : SP_U;
    const int shift = mv ? 18 : 17;
    const unsigned mask = (1u << shift) - 1u;
    const unsigned* pr = mv ? pr_m : pr_u;
    const int* bounds  = mv ? bounds_m : bounds_u;
    const int* rp = mv ? rp_m : rp_u;
    int* adj = mv ? adj_m : adj_u;
    const int n_tot = mv ? NM : NU;
    const int nb = bb * span;
    for (int i = threadIdx.x; i < span; i += blockDim.x)
        cur[i] = (nb + i < n_tot) ? rp[nb + i] : 0;
    __syncthreads();
    const int s0 = bounds[bb], s1 = bounds[bb + 1];
    for (int i = s0 + threadIdx.x; i < s1; i += blockDim.x) {
        const unsigned w = pr[i];
        const int slot = atomicAdd(&cur[w >> shift], 1);
        adj[slot] = (int)(w & mask);
    }
}

// ---------------------------------------------------------------------------
// bf16 mean-aggregate gather. Wave layout: slot = lane>>3 (8 neighbor slots),
// col = lane&7 (8 dims = uint4 = 16B). Per 16 neighbors: 2 adj dword reads +
// 2 dwordx4 row loads (1KB/wave-instr) + unpack/acc. Butterfly over lane bits
// 3,4,5; slot 0 packs+writes the bf16 mean row (128B). agg relative to n0.
__global__ __launch_bounds__(256) void
gather_mean_bf16_kernel(const ushort_t* __restrict__ xsrc,
                        const int* __restrict__ rowptr,
                        const int* __restrict__ adj,
                        ushort_t* __restrict__ agg,
                        int n0, int n1) {
    const int lane = threadIdx.x & 63;
    const int slot = lane >> 3;
    const int col  = lane & 7;
    const int wid  = (blockIdx.x * blockDim.x + threadIdx.x) >> 6;
    const int nw   = (gridDim.x * blockDim.x) >> 6;
    for (int i = n0 + wid; i < n1; i += nw) {
        const int r0 = rowptr[i], r1 = rowptr[i + 1];
        float a[8] = {0.f, 0.f, 0.f, 0.f, 0.f, 0.f, 0.f, 0.f};
        float b[8] = {0.f, 0.f, 0.f, 0.f, 0.f, 0.f, 0.f, 0.f};
        int j = r0 + slot;
        for (; j + 8 < r1; j += 16) {
            const int s0 = adj[j];
            const int s1 = adj[j + 8];
            const uint4 v0 = ((const uint4*)(xsrc + (size_t)s0 * DIM))[col];
            const uint4 v1 = ((const uint4*)(xsrc + (size_t)s1 * DIM))[col];
            a[0] += bf_lo(v0.x); a[1] += bf_hi(v0.x);
            a[2] += bf_lo(v0.y); a[3] += bf_hi(v0.y);
            a[4] += bf_lo(v0.z); a[5] += bf_hi(v0.z);
            a[6] += bf_lo(v0.w); a[7] += bf_hi(v0.w);
            b[0] += bf_lo(v1.x); b[1] += bf_hi(v1.x);
            b[2] += bf_lo(v1.y); b[3] += bf_hi(v1.y);
            b[4] += bf_lo(v1.z); b[5] += bf_hi(v1.z);
            b[6] += bf_lo(v1.w); b[7] += bf_hi(v1.w);
        }
        if (j < r1) {
            const int s0 = adj[j];
            const uint4 v0 = ((const uint4*)(xsrc + (size_t)s0 * DIM))[col];
            a[0] += bf_lo(v0.x); a[1] += bf_hi(v0.x);
            a[2] += bf_lo(v0.y); a[3] += bf_hi(v0.y);
            a[4] += bf_lo(v0.z); a[5] += bf_hi(v0.z);
            a[6] += bf_lo(v0.w); a[7] += bf_hi(v0.w);
        }
#pragma unroll
        for (int k = 0; k < 8; ++k) a[k] += b[k];
#pragma unroll
        for (int k = 0; k < 8; ++k) {
            a[k] += __shfl_xor(a[k], 8);
            a[k] += __shfl_xor(a[k], 16);
            a[k] += __shfl_xor(a[k], 32);
        }
        if (slot == 0) {
            const float inv = 1.0f / fmaxf((float)(r1 - r0), 1.0f);
            uint4 o;
            o.x = pack_bf2(a[0] * inv, a[1] * inv);
            o.y = pack_bf2(a[2] * inv, a[3] * inv);
            o.z = pack_bf2(a[4] * inv, a[5] * inv);
            o.w = pack_bf2(a[6] * inv, a[7] * inv);
            ((uint4*)(agg + (size_t)(i - n0) * DIM))[col] = o;
        }
    }
}

// ---------------------------------------------------------------------------
// Transform tile: C[64][64] = [agg_bf | xdst][64][128] @ [Wl;Wr][128][64] + b.
// agg is bf16 (relative n0); xdst is fp32 (XBF=0) or bf16 (XBF=1), absolute.
// Outputs: optional fp32 out_f, optional bf16 out_b.
template <int RELU, int XBF>
__global__ __launch_bounds__(256) void
transform_tile_kernel(const ushort_t* __restrict__ agg,
                      const float* __restrict__ xdst_f,
                      const ushort_t* __restrict__ xdst_b,
                      const float* __restrict__ Wl,
                      const float* __restrict__ Wr,
                      const float* __restrict__ bl,
                      float* __restrict__ out_f,
                      ushort_t* __restrict__ out_b,
                      int n0, int n1) {
    __shared__ float sAX[128 * 64];
    __shared__ float sW[128 * 64];

    const int tid = threadIdx.x;
    {
        const float4* wl4 = (const float4*)Wl;
        const float4* wr4 = (const float4*)Wr;
        float4* sw4 = (float4*)sW;
#pragma unroll
        for (int i = 0; i < 4; ++i) {
            sw4[tid + 256 * i] = wl4[tid + 256 * i];
            sw4[1024 + tid + 256 * i] = wr4[tid + 256 * i];
        }
    }
    const int base = n0 + blockIdx.x * 64;
#pragma unroll
    for (int rep = 0; rep < 4; ++rep) {
        const int idx = rep * 256 + tid;
        const int ln  = idx >> 4;
        const int c   = idx & 15;
        const int node = base + ln;
        const int pc = ((((ln >> 2) ^ c) << 2) | (ln & 3));
        float4 av = make_float4(0.f, 0.f, 0.f, 0.f);
        float4 xv = make_float4(0.f, 0.f, 0.f, 0.f);
        if (node < n1) {
            const uint2 ab = ((const uint2*)(agg + (size_t)(node - n0) * DIM))[c];
            av = make_float4(bf_lo(ab.x), bf_hi(ab.x), bf_lo(ab.y), bf_hi(ab.y));
            if (XBF) {
                const uint2 xb = ((const uint2*)(xdst_b + (size_t)node * DIM))[c];
                xv = make_float4(bf_lo(xb.x), bf_hi(xb.x), bf_lo(xb.y), bf_hi(xb.y));
            } else {
                xv = ((const float4*)(xdst_f + (size_t)node * DIM))[c];
            }
        }
        sAX[(4 * c + 0) * 64 + pc] = av.x;
        sAX[(4 * c + 1) * 64 + pc] = av.y;
        sAX[(4 * c + 2) * 64 + pc] = av.z;
        sAX[(4 * c + 3) * 64 + pc] = av.w;
        sAX[(64 + 4 * c + 0) * 64 + pc] = xv.x;
        sAX[(64 + 4 * c + 1) * 64 + pc] = xv.y;
        sAX[(64 + 4 * c + 2) * 64 + pc] = xv.z;
        sAX[(64 + 4 * c + 3) * 64 + pc] = xv.w;
    }
    __syncthreads();

    const int rq = tid >> 4;
    const int cq = tid & 15;
    const float4 bv = ((const float4*)bl)[cq];
    float4 a0 = bv, a1 = bv, a2 = bv, a3 = bv;
#pragma unroll 4
    for (int k = 0; k < 128; ++k) {
        const int g = (k >> 2) & 15;
        const float4 av = *(const float4*)&sAX[k * 64 + ((rq ^ g) << 2)];
        const float4 wv = *(const float4*)&sW[k * 64 + (cq << 2)];
        a0.x += av.x * wv.x; a0.y += av.x * wv.y; a0.z += av.x * wv.z; a0.w += av.x * wv.w;
        a1.x += av.y * wv.x; a1.y += av.y * wv.y; a1.z += av.y * wv.z; a1.w += av.y * wv.w;
        a2.x += av.z * wv.x; a2.y += av.z * wv.y; a2.z += av.z * wv.z; a2.w += av.z * wv.w;
        a3.x += av.w * wv.x; a3.y += av.w * wv.y; a3.z += av.w * wv.z; a3.w += av.w * wv.w;
    }
    float4 r[4] = {a0, a1, a2, a3};
#pragma unroll
    for (int i = 0; i < 4; ++i) {
        const int node = base + 4 * rq + i;
        if (node < n1) {
            float4 v = r[i];
            if (RELU) {
                v.x = fmaxf(v.x, 0.f); v.y = fmaxf(v.y, 0.f);
                v.z = fmaxf(v.z, 0.f); v.w = fmaxf(v.w, 0.f);
            }
            if (out_f) ((float4*)(out_f + (size_t)node * DIM))[cq] = v;
            if (out_b)
                ((uint2*)(out_b + (size_t)node * DIM))[cq] =
                    make_uint2(pack_bf2(v.x, v.y), pack_bf2(v.z, v.w));
        }
    }
}

// ---------------------------------------------------------------------------
extern "C" void kernel_launch(void* const* d_in, const int* in_sizes, int n_in,
                              void* d_out, int out_size, void* d_ws, size_t ws_size,
                              hipStream_t stream) {
    const float* x_user  = (const float*)d_in[0];
    const float* x_movie = (const float*)d_in[1];
    const void*  e_src   = d_in[2];
    const void*  e_dst   = d_in[3];
    const float* W1_um_l = (const float*)d_in[4];
    const float* W1_um_r = (const float*)d_in[5];
    const float* W1_mu_l = (const float*)d_in[6];
    const float* W1_mu_r = (const float*)d_in[7];
    const float* W2_um_l = (const float*)d_in[8];
    const float* W2_um_r = (const float*)d_in[9];
    const float* W2_mu_l = (const float*)d_in[10];
    const float* W2_mu_r = (const float*)d_in[11];
    const float* b1_um = (const float*)d_in[12];
    const float* b1_mu = (const float*)d_in[13];
    const float* b2_um = (const float*)d_in[14];
    const float* b2_mu = (const float*)d_in[15];
    const int nE = in_sizes[2];
    const int cpb = (nE + G_SC - 1) / G_SC;

    // workspace carve-up (256B aligned); peak ~75.4 MB (< 78 MB proven)
    char* ws = (char*)d_ws;
    size_t off = 0;
    auto carve = [&](size_t bytes) {
        void* p = ws + off;
        off += (bytes + 255) & ~(size_t)255;
        return p;
    };
    int*      flag     = (int*)carve(4);
    int*      rp_u     = (int*)carve(((size_t)NU + 1) * 4);
    int*      rp_m     = (int*)carve(((size_t)NM + 1) * 4);
    int*      bsum_u   = (int*)carve(128 * 4);
    int*      bsum_m   = (int*)carve(128 * 4);
    int*      hist_m   = (int*)carve((size_t)MBK2 * G_SC * 4);
    int*      hist_u   = (int*)carve((size_t)MBK2 * G_SC * 4);
    int*      bounds_m = (int*)carve((MBK2 + 1) * 4);
    int*      bounds_u = (int*)carve((MBK2 + 1) * 4);
    int*      adj_u    = (int*)carve((size_t)nE * 4);
    int*      adj_m    = (int*)carve((size_t)nE * 4);
    // A1 (25.6MB): xu_bf (layer1) then u1_bf (written L1-user transforms,
    //              read L2-movie gathers)
    ushort_t* A1 = (ushort_t*)carve((size_t)NU * DIM * 2);
    // A2 (12.8MB): m1_bf (written L1-movie transforms, read L2-user gathers,
    //              and xdst for L2-movie transforms)
    ushort_t* A2 = (ushort_t*)carve((size_t)NM * DIM * 2);
    // B: phase A = pr_m|pr_u (16MB); phase B = agg_bf (6.4MB) + xm_bf (12.8MB)
    size_t b_bytes = (size_t)2 * nE * 4;
    size_t phb = ((size_t)CHK + NM) * DIM * 2;
    if (phb > b_bytes) b_bytes = phb;
    char*     B      = (char*)carve(b_bytes);
    unsigned* pr_m   = (unsigned*)B;
    unsigned* pr_u   = (unsigned*)(B + (size_t)nE * 4);
    ushort_t* agg_bf = (ushort_t*)B;
    ushort_t* xm_bf  = (ushort_t*)(B + (size_t)CHK * DIM * 2);
    ushort_t* xu_bf  = A1;
    ushort_t* u1_bf  = A1;
    ushort_t* m1_bf  = A2;

    float* u2 = (float*)d_out;                    // [NU,64]; also u1 (in-place)
    float* m2 = (float*)d_out + (size_t)NU * DIM; // [NM,64]
    float* u1 = u2;

    // ---- build CSR (both directions): radix binning, zero global atomics ----
    detect_idx_kernel<<<1, 256, 0, stream>>>((const unsigned int*)e_src, flag);
    count_kernel<<<G_SC, 256, 0, stream>>>(e_src, e_dst, flag,
                                           hist_m, hist_u, nE, cpb);
    hist_scan_kernel<<<2, 1024, 0, stream>>>(hist_m, hist_u,
                                             bounds_m, bounds_u, nE);
    pair_scatter_kernel<<<G_SC, 256, 0, stream>>>(e_src, e_dst, flag,
                                                  hist_m, hist_u, pr_m, pr_u,
                                                  nE, cpb);
    deg_count_kernel<<<2 * MBK2, 1024, 0, stream>>>(pr_m, pr_u,
                                                    bounds_m, bounds_u,
                                                    rp_m, rp_u);

    const int nbU = (NU + SCAN_CHUNK - 1) / SCAN_CHUNK;
    const int nbM = (NM + SCAN_CHUNK - 1) / SCAN_CHUNK;
    scan_block_sums<<<nbU, 256, 0, stream>>>(rp_u, bsum_u, NU);
    scan_block_sums<<<nbM, 256, 0, stream>>>(rp_m, bsum_m, NM);
    scan_bsum<<<1, 64, 0, stream>>>(bsum_u, nbU);
    scan_bsum<<<1, 64, 0, stream>>>(bsum_m, nbM);
    scan_apply<<<nbU, 256, 0, stream>>>(rp_u, bsum_u, NU, nE);
    scan_apply<<<nbM, 256, 0, stream>>>(rp_m, bsum_m, NM, nE);

    bucket_fill_kernel<<<2 * MBK2, 1024, 0, stream>>>(pr_m, pr_u,
                                                      bounds_m, bounds_u,
                                                      rp_m, rp_u, adj_m, adj_u);
    // pr_m/pr_u dead from here; B switches to agg_bf/xm_bf.

    // ---- bf16 source copies ----
    f32_to_bf16_kernel<<<2048, 256, 0, stream>>>((const float4*)x_user,
                                                 (uint2*)xu_bf, NU * 16);
    f32_to_bf16_kernel<<<2048, 256, 0, stream>>>((const float4*)x_movie,
                                                 (uint2*)xm_bf, NM * 16);

    const int GB = 12500;                  // 50k waves = 1 node/wave per chunk
    const int TB = (CHK + 63) / 64;

    // ---- layer 1: movie (gather x_user via xu_bf) -> m1_bf only ----
    for (int c = 0; c < 2; ++c) {
        const int n0 = c * CHK, n1 = min(NM, n0 + CHK);
        gather_mean_bf16_kernel<<<GB, 256, 0, stream>>>(xu_bf, rp_m, adj_m,
                                                        agg_bf, n0, n1);
        transform_tile_kernel<1, 0><<<TB, 256, 0, stream>>>(agg_bf, x_movie,
            nullptr, W1_um_l, W1_um_r, b1_um, nullptr, m1_bf, n0, n1);
    }
    // ---- layer 1: user (gather x_movie via xm_bf) -> u1 fp32 + u1_bf ----
    // NOTE: u1_bf overwrites xu_bf (A1) -- xu_bf is dead after the loop above.
    for (int c = 0; c < 4; ++c) {
        const int n0 = c * CHK, n1 = min(NU, n0 + CHK);
        gather_mean_bf16_kernel<<<GB, 256, 0, stream>>>(xm_bf, rp_u, adj_u,
                                                        agg_bf, n0, n1);
        transform_tile_kernel<1, 0><<<TB, 256, 0, stream>>>(agg_bf, x_user,
            nullptr, W1_mu_l, W1_mu_r, b1_mu, u1, u1_bf, n0, n1);
    }
    // ---- layer 2: movie (gather u1_bf; xdst = m1_bf) -> m2 fp32 ----
    for (int c = 0; c < 2; ++c) {
        const int n0 = c * CHK, n1 = min(NM, n0 + CHK);
        gather_mean_bf16_kernel<<<GB, 256, 0, stream>>>(u1_bf, rp_m, adj_m,
                                                        agg_bf, n0, n1);
        transform_tile_kernel<0, 1><<<TB, 256, 0, stream>>>(agg_bf, nullptr,
            m1_bf, W2_um_l, W2_um_r, b2_um, m2, nullptr, n0, n1);
    }
    // ---- layer 2: user (gather m1_bf; xdst = u1 fp32) -> u2 in-place ----
    for (int c = 0; c < 4; ++c) {
        const int n0 = c * CHK, n1 = min(NU, n0 + CHK);
        gather_mean_bf16_kernel<<<GB, 256, 0, stream>>>(m1_bf, rp_u, adj_u,
                                                        agg_bf, n0, n1);
        transform_tile_kernel<0, 0><<<TB, 256, 0, stream>>>(agg_bf, u1,
            nullptr, W2_mu_l, W2_mu_r, b2_mu, u2, nullptr, n0, n1);
    }
}

// Round 11
// 534.570 us; speedup vs baseline: 1.2404x; 1.2404x over previous
//
#include <hip/hip_runtime.h>
#include <stdint.h>

#define NU 200000
#define NM 100000
#define DIM 64
#define MBK2 64          // buckets per direction
#define SP_M 1563        // movie node span per bucket (ceil(NM/64))
#define SP_U 3125        // user  node span per bucket (NU/64)
#define G_SC 1024        // blocks for count/pair_scatter (fixed chunk assignment)

typedef unsigned short ushort_t;

// ---------------------------------------------------------------------------
// bf16 helpers (RNE)
__device__ __forceinline__ unsigned pack_bf2(float lo, float hi) {
    unsigned ul = __float_as_uint(lo); ul += 0x7fffu + ((ul >> 16) & 1u);
    unsigned uh = __float_as_uint(hi); uh += 0x7fffu + ((uh >> 16) & 1u);
    return (ul >> 16) | (uh & 0xffff0000u);
}
__device__ __forceinline__ float bf_lo(unsigned u) { return __uint_as_float(u << 16); }
__device__ __forceinline__ float bf_hi(unsigned u) { return __uint_as_float(u & 0xffff0000u); }

// ---------------------------------------------------------------------------
// Detect whether edge index arrays are int64 or int32.
__global__ void detect_idx_kernel(const unsigned int* __restrict__ words,
                                  int* __restrict__ flag) {
    __shared__ int nz;
    if (threadIdx.x == 0) nz = 0;
    __syncthreads();
    for (int i = threadIdx.x; i < 2048; i += blockDim.x)
        if (words[2 * i + 1] != 0u) nz = 1;
    __syncthreads();
    if (threadIdx.x == 0) *flag = (nz == 0) ? 1 : 0;   // 1 => int64
}

__device__ __forceinline__ int load_idx(const void* __restrict__ p, int e, int is64) {
    if (is64) return (int)((const long long*)p)[e];
    return ((const int*)p)[e];
}

// ---------------------------------------------------------------------------
// fp32 -> bf16 (RNE) for BOTH feature tables in one dispatch.
__global__ void conv_bf16_kernel(const float4* __restrict__ xu,
                                 const float4* __restrict__ xm,
                                 uint2* __restrict__ xu_bf,
                                 uint2* __restrict__ xm_bf) {
    const int nu4 = NU * 16, nm4 = NM * 16;
    const int stride = gridDim.x * blockDim.x;
    for (int i = blockIdx.x * blockDim.x + threadIdx.x; i < nu4 + nm4; i += stride) {
        if (i < nu4) {
            const float4 v = xu[i];
            xu_bf[i] = make_uint2(pack_bf2(v.x, v.y), pack_bf2(v.z, v.w));
        } else {
            const float4 v = xm[i - nu4];
            xm_bf[i - nu4] = make_uint2(pack_bf2(v.x, v.y), pack_bf2(v.z, v.w));
        }
    }
}

// ---------------------------------------------------------------------------
// Per-block 64-bucket histograms, both directions (bucket-major layout
// hist[b*G_SC + blk]); FIXED per-block edge chunks.
__global__ void count_kernel(const void* __restrict__ es, const void* __restrict__ ed,
                             const int* __restrict__ flag,
                             int* __restrict__ hist_m, int* __restrict__ hist_u,
                             int nE, int cpb) {
    __shared__ int h[2 * MBK2];
    if (threadIdx.x < 2 * MBK2) h[threadIdx.x] = 0;
    __syncthreads();
    const int is64 = *flag;
    const int e0 = blockIdx.x * cpb;
    const int e1 = min(nE, e0 + cpb);
    for (int e = e0 + threadIdx.x; e < e1; e += blockDim.x) {
        int s = load_idx(es, e, is64);
        int d = load_idx(ed, e, is64);
        atomicAdd(&h[(unsigned)d / SP_M], 1);
        atomicAdd(&h[MBK2 + (unsigned)s / SP_U], 1);
    }
    __syncthreads();
    if (threadIdx.x < MBK2)
        hist_m[threadIdx.x * G_SC + blockIdx.x] = h[threadIdx.x];
    else if (threadIdx.x < 2 * MBK2)
        hist_u[(threadIdx.x - MBK2) * G_SC + blockIdx.x] = h[threadIdx.x];
}

// ---------------------------------------------------------------------------
// Exclusive scan of per-block bucket histogram (64*G_SC, bucket-major) in
// place; emits bounds[0..64]. 2 blocks (movie, user).
__global__ __launch_bounds__(1024) void
hist_scan_kernel(int* __restrict__ hist_m, int* __restrict__ hist_u,
                 int* __restrict__ bounds_m, int* __restrict__ bounds_u, int nE) {
    int* hist   = (blockIdx.x == 0) ? hist_m : hist_u;
    int* bounds = (blockIdx.x == 0) ? bounds_m : bounds_u;
    const int t = threadIdx.x;          // 1024 threads x 64 = 64*G_SC
    const int base = t * 64;
    int v[64];
    int tot = 0;
#pragma unroll
    for (int k = 0; k < 64; ++k) { v[k] = hist[base + k]; tot += v[k]; }
    __shared__ int sc[1024];
    sc[t] = tot;
    __syncthreads();
    for (int off = 1; off < 1024; off <<= 1) {
        int x = (t >= off) ? sc[t - off] : 0;
        __syncthreads();
        sc[t] += x;
        __syncthreads();
    }
    int excl = sc[t] - tot;
#pragma unroll
    for (int k = 0; k < 64; ++k) { int tmp = v[k]; hist[base + k] = excl; excl += tmp; }
    __syncthreads();
    if (t < MBK2) bounds[t] = hist[t * G_SC];
    else if (t == MBK2) bounds[MBK2] = nE;
}

// ---------------------------------------------------------------------------
// Level-1 scatter, deterministic (LDS cursors, exclusive per-bucket chunks).
__global__ void pair_scatter_kernel(const void* __restrict__ es,
                                    const void* __restrict__ ed,
                                    const int* __restrict__ flag,
                                    const int* __restrict__ hist_m,
                                    const int* __restrict__ hist_u,
                                    unsigned* __restrict__ pr_m,
                                    unsigned* __restrict__ pr_u,
                                    int nE, int cpb) {
    __shared__ int cur[2 * MBK2];
    if (threadIdx.x < MBK2)
        cur[threadIdx.x] = hist_m[threadIdx.x * G_SC + blockIdx.x];
    else if (threadIdx.x < 2 * MBK2)
        cur[threadIdx.x] = hist_u[(threadIdx.x - MBK2) * G_SC + blockIdx.x];
    __syncthreads();
    const int is64 = *flag;
    const int e0 = blockIdx.x * cpb;
    const int e1 = min(nE, e0 + cpb);
    for (int e = e0 + threadIdx.x; e < e1; e += blockDim.x) {
        const int s = load_idx(es, e, is64);
        const int d = load_idx(ed, e, is64);
        const int b0 = (unsigned)d / SP_M;
        const int b1 = (unsigned)s / SP_U;
        const int p0 = atomicAdd(&cur[b0], 1);
        pr_m[p0] = ((unsigned)(d - b0 * SP_M) << 18) | (unsigned)s;
        const int p1 = atomicAdd(&cur[MBK2 + b1], 1);
        pr_u[p1] = ((unsigned)(s - b1 * SP_U) << 17) | (unsigned)d;
    }
}

// ---------------------------------------------------------------------------
// Merged CSR build: ONE block per bucket does (1) LDS degree histogram over
// its node span, (2) LDS exclusive scan -> rowptr[node] = bounds[b] + prefix
// (coalesced global write), (3) adj fill via LDS cursors into the bucket's
// XCD-exclusive contiguous adj region. Replaces deg_count + 3 scan kernels +
// bucket_fill (5 dispatches + global scan traffic).
__global__ __launch_bounds__(1024) void
build_csr_kernel(const unsigned* __restrict__ pr_m, const unsigned* __restrict__ pr_u,
                 const int* __restrict__ bounds_m, const int* __restrict__ bounds_u,
                 int* __restrict__ rp_m, int* __restrict__ rp_u,
                 int* __restrict__ adj_m, int* __restrict__ adj_u, int nE) {
    __shared__ int cur[SP_U];
    __shared__ int ps[1024];
    const int t = threadIdx.x;
    const int b = blockIdx.x;
    const bool mv = (b < MBK2);
    const int bb = mv ? b : b - MBK2;
    const int span  = mv ? SP_M : SP_U;
    const int shift = mv ? 18 : 17;
    const unsigned mask = (1u << shift) - 1u;
    const unsigned* pr = mv ? pr_m : pr_u;
    const int* bounds  = mv ? bounds_m : bounds_u;
    int* rp  = mv ? rp_m : rp_u;
    int* adj = mv ? adj_m : adj_u;
    const int n_tot = mv ? NM : NU;
    const int nb = bb * span;
    const int s0 = bounds[bb], s1 = bounds[bb + 1];

    for (int i = t; i < span; i += 1024) cur[i] = 0;
    __syncthreads();
    for (int i = s0 + t; i < s1; i += 1024)
        atomicAdd(&cur[pr[i] >> shift], 1);
    __syncthreads();
    // exclusive scan of cur[0..span) (4 elems/thread + block scan)
    int v[4];
    int loc = 0;
#pragma unroll
    for (int k = 0; k < 4; ++k) {
        const int i = t * 4 + k;
        v[k] = (i < span) ? cur[i] : 0;
        loc += v[k];
    }
    ps[t] = loc;
    __syncthreads();
    for (int off = 1; off < 1024; off <<= 1) {
        int x = (t >= off) ? ps[t - off] : 0;
        __syncthreads();
        ps[t] += x;
        __syncthreads();
    }
    int run = s0 + ps[t] - loc;
#pragma unroll
    for (int k = 0; k < 4; ++k) {
        const int i = t * 4 + k;
        if (i < span) {
            if (nb + i < n_tot) rp[nb + i] = run;
            cur[i] = run;
            run += v[k];
        }
    }
    if (bb == MBK2 - 1 && t == 0) rp[n_tot] = nE;   // sentinel
    __syncthreads();
    for (int i = s0 + t; i < s1; i += 1024) {
        const unsigned w = pr[i];
        const int slot = atomicAdd(&cur[w >> shift], 1);
        adj[slot] = (int)(w & mask);
    }
}

// ---------------------------------------------------------------------------
// bf16 mean-aggregate gather. Wave layout: slot = lane>>3 (8 neighbor slots),
// col = lane&7 (8 dims = uint4 = 16B). 16 neighbors in flight per wave.
__global__ __launch_bounds__(256) void
gather_mean_bf16_kernel(const ushort_t* __restrict__ xsrc,
                        const int* __restrict__ rowptr,
                        const int* __restrict__ adj,
                        ushort_t* __restrict__ agg,
                        int n0, int n1) {
    const int lane = threadIdx.x & 63;
    const int slot = lane >> 3;
    const int col  = lane & 7;
    const int wid  = (blockIdx.x * blockDim.x + threadIdx.x) >> 6;
    const int nw   = (gridDim.x * blockDim.x) >> 6;
    for (int i = n0 + wid; i < n1; i += nw) {
        const int r0 = rowptr[i], r1 = rowptr[i + 1];
        float a[8] = {0.f, 0.f, 0.f, 0.f, 0.f, 0.f, 0.f, 0.f};
        float b[8] = {0.f, 0.f, 0.f, 0.f, 0.f, 0.f, 0.f, 0.f};
        int j = r0 + slot;
        for (; j + 8 < r1; j += 16) {
            const int s0 = adj[j];
            const int s1 = adj[j + 8];
            const uint4 v0 = ((const uint4*)(xsrc + (size_t)s0 * DIM))[col];
            const uint4 v1 = ((const uint4*)(xsrc + (size_t)s1 * DIM))[col];
            a[0] += bf_lo(v0.x); a[1] += bf_hi(v0.x);
            a[2] += bf_lo(v0.y); a[3] += bf_hi(v0.y);
            a[4] += bf_lo(v0.z); a[5] += bf_hi(v0.z);
            a[6] += bf_lo(v0.w); a[7] += bf_hi(v0.w);
            b[0] += bf_lo(v1.x); b[1] += bf_hi(v1.x);
            b[2] += bf_lo(v1.y); b[3] += bf_hi(v1.y);
            b[4] += bf_lo(v1.z); b[5] += bf_hi(v1.z);
            b[6] += bf_lo(v1.w); b[7] += bf_hi(v1.w);
        }
        if (j < r1) {
            const int s0 = adj[j];
            const uint4 v0 = ((const uint4*)(xsrc + (size_t)s0 * DIM))[col];
            a[0] += bf_lo(v0.x); a[1] += bf_hi(v0.x);
            a[2] += bf_lo(v0.y); a[3] += bf_hi(v0.y);
            a[4] += bf_lo(v0.z); a[5] += bf_hi(v0.z);
            a[6] += bf_lo(v0.w); a[7] += bf_hi(v0.w);
        }
#pragma unroll
        for (int k = 0; k < 8; ++k) a[k] += b[k];
#pragma unroll
        for (int k = 0; k < 8; ++k) {
            a[k] += __shfl_xor(a[k], 8);
            a[k] += __shfl_xor(a[k], 16);
            a[k] += __shfl_xor(a[k], 32);
        }
        if (slot == 0) {
            const float inv = 1.0f / fmaxf((float)(r1 - r0), 1.0f);
            uint4 o;
            o.x = pack_bf2(a[0] * inv, a[1] * inv);
            o.y = pack_bf2(a[2] * inv, a[3] * inv);
            o.z = pack_bf2(a[4] * inv, a[5] * inv);
            o.w = pack_bf2(a[6] * inv, a[7] * inv);
            ((uint4*)(agg + (size_t)(i - n0) * DIM))[col] = o;
        }
    }
}

// ---------------------------------------------------------------------------
// Transform tile: C[64][64] = [agg_bf | xdst_bf][64][128] @ [Wl;Wr][128][64]+b.
// agg bf16 relative n0; xdst bf16 absolute. Outputs fp32 and/or bf16.
// Safe for xdst_b == out_b on the same rows (block stages before storing).
template <int RELU>
__global__ __launch_bounds__(256) void
transform_tile_kernel(const ushort_t* __restrict__ agg,
                      const ushort_t* __restrict__ xdst_b,
                      const float* __restrict__ Wl,
                      const float* __restrict__ Wr,
                      const float* __restrict__ bl,
                      float* __restrict__ out_f,
                      ushort_t* __restrict__ out_b,
                      int n0, int n1) {
    __shared__ float sAX[128 * 64];
    __shared__ float sW[128 * 64];

    const int tid = threadIdx.x;
    {
        const float4* wl4 = (const float4*)Wl;
        const float4* wr4 = (const float4*)Wr;
        float4* sw4 = (float4*)sW;
#pragma unroll
        for (int i = 0; i < 4; ++i) {
            sw4[tid + 256 * i] = wl4[tid + 256 * i];
            sw4[1024 + tid + 256 * i] = wr4[tid + 256 * i];
        }
    }
    const int base = n0 + blockIdx.x * 64;
#pragma unroll
    for (int rep = 0; rep < 4; ++rep) {
        const int idx = rep * 256 + tid;
        const int ln  = idx >> 4;
        const int c   = idx & 15;
        const int node = base + ln;
        const int pc = ((((ln >> 2) ^ c) << 2) | (ln & 3));
        float4 av = make_float4(0.f, 0.f, 0.f, 0.f);
        float4 xv = make_float4(0.f, 0.f, 0.f, 0.f);
        if (node < n1) {
            const uint2 ab = ((const uint2*)(agg + (size_t)(node - n0) * DIM))[c];
            av = make_float4(bf_lo(ab.x), bf_hi(ab.x), bf_lo(ab.y), bf_hi(ab.y));
            const uint2 xb = ((const uint2*)(xdst_b + (size_t)node * DIM))[c];
            xv = make_float4(bf_lo(xb.x), bf_hi(xb.x), bf_lo(xb.y), bf_hi(xb.y));
        }
        sAX[(4 * c + 0) * 64 + pc] = av.x;
        sAX[(4 * c + 1) * 64 + pc] = av.y;
        sAX[(4 * c + 2) * 64 + pc] = av.z;
        sAX[(4 * c + 3) * 64 + pc] = av.w;
        sAX[(64 + 4 * c + 0) * 64 + pc] = xv.x;
        sAX[(64 + 4 * c + 1) * 64 + pc] = xv.y;
        sAX[(64 + 4 * c + 2) * 64 + pc] = xv.z;
        sAX[(64 + 4 * c + 3) * 64 + pc] = xv.w;
    }
    __syncthreads();

    const int rq = tid >> 4;
    const int cq = tid & 15;
    const float4 bv = ((const float4*)bl)[cq];
    float4 a0 = bv, a1 = bv, a2 = bv, a3 = bv;
#pragma unroll 4
    for (int k = 0; k < 128; ++k) {
        const int g = (k >> 2) & 15;
        const float4 av = *(const float4*)&sAX[k * 64 + ((rq ^ g) << 2)];
        const float4 wv = *(const float4*)&sW[k * 64 + (cq << 2)];
        a0.x += av.x * wv.x; a0.y += av.x * wv.y; a0.z += av.x * wv.z; a0.w += av.x * wv.w;
        a1.x += av.y * wv.x; a1.y += av.y * wv.y; a1.z += av.y * wv.z; a1.w += av.y * wv.w;
        a2.x += av.z * wv.x; a2.y += av.z * wv.y; a2.z += av.z * wv.z; a2.w += av.z * wv.w;
        a3.x += av.w * wv.x; a3.y += av.w * wv.y; a3.z += av.w * wv.z; a3.w += av.w * wv.w;
    }
    float4 r[4] = {a0, a1, a2, a3};
#pragma unroll
    for (int i = 0; i < 4; ++i) {
        const int node = base + 4 * rq + i;
        if (node < n1) {
            float4 v = r[i];
            if (RELU) {
                v.x = fmaxf(v.x, 0.f); v.y = fmaxf(v.y, 0.f);
                v.z = fmaxf(v.z, 0.f); v.w = fmaxf(v.w, 0.f);
            }
            if (out_f) ((float4*)(out_f + (size_t)node * DIM))[cq] = v;
            if (out_b)
                ((uint2*)(out_b + (size_t)node * DIM))[cq] =
                    make_uint2(pack_bf2(v.x, v.y), pack_bf2(v.z, v.w));
        }
    }
}

// ---------------------------------------------------------------------------
extern "C" void kernel_launch(void* const* d_in, const int* in_sizes, int n_in,
                              void* d_out, int out_size, void* d_ws, size_t ws_size,
                              hipStream_t stream) {
    const float* x_user  = (const float*)d_in[0];
    const float* x_movie = (const float*)d_in[1];
    const void*  e_src   = d_in[2];
    const void*  e_dst   = d_in[3];
    const float* W1_um_l = (const float*)d_in[4];
    const float* W1_um_r = (const float*)d_in[5];
    const float* W1_mu_l = (const float*)d_in[6];
    const float* W1_mu_r = (const float*)d_in[7];
    const float* W2_um_l = (const float*)d_in[8];
    const float* W2_um_r = (const float*)d_in[9];
    const float* W2_mu_l = (const float*)d_in[10];
    const float* W2_mu_r = (const float*)d_in[11];
    const float* b1_um = (const float*)d_in[12];
    const float* b1_mu = (const float*)d_in[13];
    const float* b2_um = (const float*)d_in[14];
    const float* b2_mu = (const float*)d_in[15];
    const int nE = in_sizes[2];
    const int cpb = (nE + G_SC - 1) / G_SC;

    auto al = [](size_t b) { return (b + 255) & ~(size_t)255; };
    // fixed region + A1 (xu_bf/u1_bf) + A2 (m1_bf) sizes
    const size_t fixed_b = al(4) + al(((size_t)NU + 1) * 4) + al(((size_t)NM + 1) * 4)
                         + 2 * al((size_t)MBK2 * G_SC * 4) + 2 * al((MBK2 + 1) * 4)
                         + 2 * al((size_t)nE * 4);
    const size_t a1_b = al((size_t)NU * DIM * 2);
    const size_t a2_b = al((size_t)NM * DIM * 2);
    const size_t pair_b = (size_t)2 * nE * 4;
    // choose largest chunk size whose overlay fits ws_size
    int CHKr = 50000;
    {
        const int cand[3] = {200000, 100000, 50000};
        for (int k = 0; k < 3; ++k) {
            size_t bphase = (size_t)cand[k] * DIM * 2 + (size_t)NM * DIM * 2 + 1024;
            size_t need = fixed_b + a1_b + a2_b +
                          al(bphase > pair_b ? bphase : pair_b) + 4096;
            if (need <= ws_size) { CHKr = cand[k]; break; }
        }
    }

    // workspace carve-up (256B aligned)
    char* ws = (char*)d_ws;
    size_t off = 0;
    auto carve = [&](size_t bytes) {
        void* p = ws + off;
        off += al(bytes);
        return p;
    };
    int*      flag     = (int*)carve(4);
    int*      rp_u     = (int*)carve(((size_t)NU + 1) * 4);
    int*      rp_m     = (int*)carve(((size_t)NM + 1) * 4);
    int*      hist_m   = (int*)carve((size_t)MBK2 * G_SC * 4);
    int*      hist_u   = (int*)carve((size_t)MBK2 * G_SC * 4);
    int*      bounds_m = (int*)carve((MBK2 + 1) * 4);
    int*      bounds_u = (int*)carve((MBK2 + 1) * 4);
    int*      adj_u    = (int*)carve((size_t)nE * 4);
    int*      adj_m    = (int*)carve((size_t)nE * 4);
    ushort_t* A1 = (ushort_t*)carve((size_t)NU * DIM * 2);  // xu_bf then u1_bf
    ushort_t* A2 = (ushort_t*)carve((size_t)NM * DIM * 2);  // m1_bf
    size_t bphase = (size_t)CHKr * DIM * 2 + (size_t)NM * DIM * 2 + 1024;
    char*     B      = (char*)carve(bphase > pair_b ? bphase : pair_b);
    unsigned* pr_m   = (unsigned*)B;                        // phase A
    unsigned* pr_u   = (unsigned*)(B + (size_t)nE * 4);     // phase A
    ushort_t* agg_bf = (ushort_t*)B;                        // phase B
    ushort_t* xm_bf  = (ushort_t*)(B + al((size_t)CHKr * DIM * 2)); // phase B
    ushort_t* xu_bf  = A1;
    ushort_t* u1_bf  = A1;
    ushort_t* m1_bf  = A2;

    float* u2 = (float*)d_out;                    // [NU,64]
    float* m2 = (float*)d_out + (size_t)NU * DIM; // [NM,64]

    // ---- build CSR (both directions): radix binning, zero global atomics ----
    detect_idx_kernel<<<1, 256, 0, stream>>>((const unsigned int*)e_src, flag);
    count_kernel<<<G_SC, 256, 0, stream>>>(e_src, e_dst, flag,
                                           hist_m, hist_u, nE, cpb);
    hist_scan_kernel<<<2, 1024, 0, stream>>>(hist_m, hist_u,
                                             bounds_m, bounds_u, nE);
    pair_scatter_kernel<<<G_SC, 256, 0, stream>>>(e_src, e_dst, flag,
                                                  hist_m, hist_u, pr_m, pr_u,
                                                  nE, cpb);
    // merged: degree hist + in-bucket scan -> rowptr, + adj fill
    build_csr_kernel<<<2 * MBK2, 1024, 0, stream>>>(pr_m, pr_u,
                                                    bounds_m, bounds_u,
                                                    rp_m, rp_u, adj_m, adj_u, nE);
    // pr_m/pr_u dead from here; B switches to agg_bf/xm_bf.

    // ---- bf16 source copies (one dispatch) ----
    conv_bf16_kernel<<<2048, 256, 0, stream>>>((const float4*)x_user,
                                               (const float4*)x_movie,
                                               (uint2*)xu_bf, (uint2*)xm_bf);

    auto run_dir = [&](const ushort_t* src_bf, const int* rp, const int* adj,
                       const ushort_t* xdst_bf, const float* Wl, const float* Wr,
                       const float* bl, float* outf, ushort_t* outb,
                       int n_tot, int relu) {
        for (int n0 = 0; n0 < n_tot; n0 += CHKr) {
            const int n1 = min(n_tot, n0 + CHKr);
            const int gb = (n1 - n0 + 3) / 4;       // 1 node/wave
            const int tb = (n1 - n0 + 63) / 64;
            gather_mean_bf16_kernel<<<gb, 256, 0, stream>>>(src_bf, rp, adj,
                                                            agg_bf, n0, n1);
            if (relu)
                transform_tile_kernel<1><<<tb, 256, 0, stream>>>(agg_bf, xdst_bf,
                    Wl, Wr, bl, outf, outb, n0, n1);
            else
                transform_tile_kernel<0><<<tb, 256, 0, stream>>>(agg_bf, xdst_bf,
                    Wl, Wr, bl, outf, outb, n0, n1);
        }
    };

    // ---- layer 1 (bf16 intermediates only) ----
    // movie: gather xu_bf -> m1_bf
    run_dir(xu_bf, rp_m, adj_m, xm_bf, W1_um_l, W1_um_r, b1_um,
            nullptr, m1_bf, NM, 1);
    // user: gather xm_bf; xdst = xu_bf, out = u1_bf (same buffer, row-in-place)
    run_dir(xm_bf, rp_u, adj_u, xu_bf, W1_mu_l, W1_mu_r, b1_mu,
            nullptr, u1_bf, NU, 1);
    // ---- layer 2 (fp32 outputs straight to d_out) ----
    // movie: gather u1_bf; xdst = m1_bf -> m2
    run_dir(u1_bf, rp_m, adj_m, m1_bf, W2_um_l, W2_um_r, b2_um,
            m2, nullptr, NM, 0);
    // user: gather m1_bf; xdst = u1_bf -> u2
    run_dir(m1_bf, rp_u, adj_u, u1_bf, W2_mu_l, W2_mu_r, b2_mu,
            u2, nullptr, NU, 0);
}

// Round 12
// 534.132 us; speedup vs baseline: 1.2414x; 1.0008x over previous
//
#include <hip/hip_runtime.h>
#include <stdint.h>

#define NU 200000
#define NM 100000
#define DIM 64
#define MBK2 64          // buckets per direction
#define SP_M 1563        // movie node span per bucket (ceil(NM/64))
#define SP_U 3125        // user  node span per bucket (NU/64)
#define G_SC 1024        // blocks for count/pair_scatter (fixed chunk assignment)

typedef unsigned short ushort_t;

// ---------------------------------------------------------------------------
// bf16 helpers (RNE)
__device__ __forceinline__ unsigned pack_bf2(float lo, float hi) {
    unsigned ul = __float_as_uint(lo); ul += 0x7fffu + ((ul >> 16) & 1u);
    unsigned uh = __float_as_uint(hi); uh += 0x7fffu + ((uh >> 16) & 1u);
    return (ul >> 16) | (uh & 0xffff0000u);
}
__device__ __forceinline__ float bf_lo(unsigned u) { return __uint_as_float(u << 16); }
__device__ __forceinline__ float bf_hi(unsigned u) { return __uint_as_float(u & 0xffff0000u); }

// v_dot2_f32_bf16: acc += pair.lo*sel.lo + pair.hi*sel.hi  (1 VALU op).
// sel = (1.0bf,0) extracts lo; sel = (0,1.0bf) extracts hi.
__device__ __forceinline__ void dot2_acc(float& acc, unsigned pair, unsigned sel) {
    asm("v_dot2_f32_bf16 %0, %1, %2, %0" : "+v"(acc) : "v"(pair), "v"(sel));
}

// ---------------------------------------------------------------------------
// Detect whether edge index arrays are int64 or int32.
__global__ void detect_idx_kernel(const unsigned int* __restrict__ words,
                                  int* __restrict__ flag) {
    __shared__ int nz;
    if (threadIdx.x == 0) nz = 0;
    __syncthreads();
    for (int i = threadIdx.x; i < 2048; i += blockDim.x)
        if (words[2 * i + 1] != 0u) nz = 1;
    __syncthreads();
    if (threadIdx.x == 0) *flag = (nz == 0) ? 1 : 0;   // 1 => int64
}

__device__ __forceinline__ int load_idx(const void* __restrict__ p, int e, int is64) {
    if (is64) return (int)((const long long*)p)[e];
    return ((const int*)p)[e];
}

// ---------------------------------------------------------------------------
// fp32 -> bf16 (RNE) for BOTH feature tables in one dispatch.
__global__ void conv_bf16_kernel(const float4* __restrict__ xu,
                                 const float4* __restrict__ xm,
                                 uint2* __restrict__ xu_bf,
                                 uint2* __restrict__ xm_bf) {
    const int nu4 = NU * 16, nm4 = NM * 16;
    const int stride = gridDim.x * blockDim.x;
    for (int i = blockIdx.x * blockDim.x + threadIdx.x; i < nu4 + nm4; i += stride) {
        if (i < nu4) {
            const float4 v = xu[i];
            xu_bf[i] = make_uint2(pack_bf2(v.x, v.y), pack_bf2(v.z, v.w));
        } else {
            const float4 v = xm[i - nu4];
            xm_bf[i - nu4] = make_uint2(pack_bf2(v.x, v.y), pack_bf2(v.z, v.w));
        }
    }
}

// ---------------------------------------------------------------------------
// Per-block 64-bucket histograms, both directions (bucket-major layout
// hist[b*G_SC + blk]); FIXED per-block edge chunks.
__global__ void count_kernel(const void* __restrict__ es, const void* __restrict__ ed,
                             const int* __restrict__ flag,
                             int* __restrict__ hist_m, int* __restrict__ hist_u,
                             int nE, int cpb) {
    __shared__ int h[2 * MBK2];
    if (threadIdx.x < 2 * MBK2) h[threadIdx.x] = 0;
    __syncthreads();
    const int is64 = *flag;
    const int e0 = blockIdx.x * cpb;
    const int e1 = min(nE, e0 + cpb);
    for (int e = e0 + threadIdx.x; e < e1; e += blockDim.x) {
        int s = load_idx(es, e, is64);
        int d = load_idx(ed, e, is64);
        atomicAdd(&h[(unsigned)d / SP_M], 1);
        atomicAdd(&h[MBK2 + (unsigned)s / SP_U], 1);
    }
    __syncthreads();
    if (threadIdx.x < MBK2)
        hist_m[threadIdx.x * G_SC + blockIdx.x] = h[threadIdx.x];
    else if (threadIdx.x < 2 * MBK2)
        hist_u[(threadIdx.x - MBK2) * G_SC + blockIdx.x] = h[threadIdx.x];
}

// ---------------------------------------------------------------------------
// Exclusive scan of per-block bucket histogram (64*G_SC, bucket-major) in
// place; emits bounds[0..64]. 2 blocks (movie, user).
__global__ __launch_bounds__(1024) void
hist_scan_kernel(int* __restrict__ hist_m, int* __restrict__ hist_u,
                 int* __restrict__ bounds_m, int* __restrict__ bounds_u, int nE) {
    int* hist   = (blockIdx.x == 0) ? hist_m : hist_u;
    int* bounds = (blockIdx.x == 0) ? bounds_m : bounds_u;
    const int t = threadIdx.x;          // 1024 threads x 64 = 64*G_SC
    const int base = t * 64;
    int v[64];
    int tot = 0;
#pragma unroll
    for (int k = 0; k < 64; ++k) { v[k] = hist[base + k]; tot += v[k]; }
    __shared__ int sc[1024];
    sc[t] = tot;
    __syncthreads();
    for (int off = 1; off < 1024; off <<= 1) {
        int x = (t >= off) ? sc[t - off] : 0;
        __syncthreads();
        sc[t] += x;
        __syncthreads();
    }
    int excl = sc[t] - tot;
#pragma unroll
    for (int k = 0; k < 64; ++k) { int tmp = v[k]; hist[base + k] = excl; excl += tmp; }
    __syncthreads();
    if (t < MBK2) bounds[t] = hist[t * G_SC];
    else if (t == MBK2) bounds[MBK2] = nE;
}

// ---------------------------------------------------------------------------
// Level-1 scatter, deterministic (LDS cursors, exclusive per-bucket chunks).
__global__ void pair_scatter_kernel(const void* __restrict__ es,
                                    const void* __restrict__ ed,
                                    const int* __restrict__ flag,
                                    const int* __restrict__ hist_m,
                                    const int* __restrict__ hist_u,
                                    unsigned* __restrict__ pr_m,
                                    unsigned* __restrict__ pr_u,
                                    int nE, int cpb) {
    __shared__ int cur[2 * MBK2];
    if (threadIdx.x < MBK2)
        cur[threadIdx.x] = hist_m[threadIdx.x * G_SC + blockIdx.x];
    else if (threadIdx.x < 2 * MBK2)
        cur[threadIdx.x] = hist_u[(threadIdx.x - MBK2) * G_SC + blockIdx.x];
    __syncthreads();
    const int is64 = *flag;
    const int e0 = blockIdx.x * cpb;
    const int e1 = min(nE, e0 + cpb);
    for (int e = e0 + threadIdx.x; e < e1; e += blockDim.x) {
        const int s = load_idx(es, e, is64);
        const int d = load_idx(ed, e, is64);
        const int b0 = (unsigned)d / SP_M;
        const int b1 = (unsigned)s / SP_U;
        const int p0 = atomicAdd(&cur[b0], 1);
        pr_m[p0] = ((unsigned)(d - b0 * SP_M) << 18) | (unsigned)s;
        const int p1 = atomicAdd(&cur[MBK2 + b1], 1);
        pr_u[p1] = ((unsigned)(s - b1 * SP_U) << 17) | (unsigned)d;
    }
}

// ---------------------------------------------------------------------------
// Merged CSR build: ONE block per bucket does (1) LDS degree histogram over
// its node span, (2) LDS exclusive scan -> rowptr[node] = bounds[b] + prefix
// (coalesced global write), (3) adj fill via LDS cursors into the bucket's
// XCD-exclusive contiguous adj region.
__global__ __launch_bounds__(1024) void
build_csr_kernel(const unsigned* __restrict__ pr_m, const unsigned* __restrict__ pr_u,
                 const int* __restrict__ bounds_m, const int* __restrict__ bounds_u,
                 int* __restrict__ rp_m, int* __restrict__ rp_u,
                 int* __restrict__ adj_m, int* __restrict__ adj_u, int nE) {
    __shared__ int cur[SP_U];
    __shared__ int ps[1024];
    const int t = threadIdx.x;
    const int b = blockIdx.x;
    const bool mv = (b < MBK2);
    const int bb = mv ? b : b - MBK2;
    const int span  = mv ? SP_M : SP_U;
    const int shift = mv ? 18 : 17;
    const unsigned mask = (1u << shift) - 1u;
    const unsigned* pr = mv ? pr_m : pr_u;
    const int* bounds  = mv ? bounds_m : bounds_u;
    int* rp  = mv ? rp_m : rp_u;
    int* adj = mv ? adj_m : adj_u;
    const int n_tot = mv ? NM : NU;
    const int nb = bb * span;
    const int s0 = bounds[bb], s1 = bounds[bb + 1];

    for (int i = t; i < span; i += 1024) cur[i] = 0;
    __syncthreads();
    for (int i = s0 + t; i < s1; i += 1024)
        atomicAdd(&cur[pr[i] >> shift], 1);
    __syncthreads();
    int v[4];
    int loc = 0;
#pragma unroll
    for (int k = 0; k < 4; ++k) {
        const int i = t * 4 + k;
        v[k] = (i < span) ? cur[i] : 0;
        loc += v[k];
    }
    ps[t] = loc;
    __syncthreads();
    for (int off = 1; off < 1024; off <<= 1) {
        int x = (t >= off) ? ps[t - off] : 0;
        __syncthreads();
        ps[t] += x;
        __syncthreads();
    }
    int run = s0 + ps[t] - loc;
#pragma unroll
    for (int k = 0; k < 4; ++k) {
        const int i = t * 4 + k;
        if (i < span) {
            if (nb + i < n_tot) rp[nb + i] = run;
            cur[i] = run;
            run += v[k];
        }
    }
    if (bb == MBK2 - 1 && t == 0) rp[n_tot] = nE;   // sentinel
    __syncthreads();
    for (int i = s0 + t; i < s1; i += 1024) {
        const unsigned w = pr[i];
        const int slot = atomicAdd(&cur[w >> shift], 1);
        adj[slot] = (int)(w & mask);
    }
}

// ---------------------------------------------------------------------------
// bf16 mean-aggregate gather with v_dot2_f32_bf16 accumulate (1 VALU op per
// bf16 element vs 2 for unpack+add). Wave layout: slot = lane>>3 (8 neighbor
// slots), col = lane&7 (8 dims = uint4 = 16B). 16 neighbors in flight.
__global__ __launch_bounds__(256) void
gather_mean_bf16_kernel(const ushort_t* __restrict__ xsrc,
                        const int* __restrict__ rowptr,
                        const int* __restrict__ adj,
                        ushort_t* __restrict__ agg,
                        int n0, int n1) {
    const unsigned SEL_LO = 0x00003f80u;   // bf16 (1.0, 0)
    const unsigned SEL_HI = 0x3f800000u;   // bf16 (0, 1.0)
    const int lane = threadIdx.x & 63;
    const int slot = lane >> 3;
    const int col  = lane & 7;
    const int wid  = (blockIdx.x * blockDim.x + threadIdx.x) >> 6;
    const int nw   = (gridDim.x * blockDim.x) >> 6;
    for (int i = n0 + wid; i < n1; i += nw) {
        const int r0 = rowptr[i], r1 = rowptr[i + 1];
        float a[8] = {0.f, 0.f, 0.f, 0.f, 0.f, 0.f, 0.f, 0.f};
        float b[8] = {0.f, 0.f, 0.f, 0.f, 0.f, 0.f, 0.f, 0.f};
        int j = r0 + slot;
        for (; j + 8 < r1; j += 16) {
            const int s0 = adj[j];
            const int s1 = adj[j + 8];
            const uint4 v0 = ((const uint4*)(xsrc + (size_t)s0 * DIM))[col];
            const uint4 v1 = ((const uint4*)(xsrc + (size_t)s1 * DIM))[col];
            dot2_acc(a[0], v0.x, SEL_LO); dot2_acc(a[1], v0.x, SEL_HI);
            dot2_acc(a[2], v0.y, SEL_LO); dot2_acc(a[3], v0.y, SEL_HI);
            dot2_acc(a[4], v0.z, SEL_LO); dot2_acc(a[5], v0.z, SEL_HI);
            dot2_acc(a[6], v0.w, SEL_LO); dot2_acc(a[7], v0.w, SEL_HI);
            dot2_acc(b[0], v1.x, SEL_LO); dot2_acc(b[1], v1.x, SEL_HI);
            dot2_acc(b[2], v1.y, SEL_LO); dot2_acc(b[3], v1.y, SEL_HI);
            dot2_acc(b[4], v1.z, SEL_LO); dot2_acc(b[5], v1.z, SEL_HI);
            dot2_acc(b[6], v1.w, SEL_LO); dot2_acc(b[7], v1.w, SEL_HI);
        }
        if (j < r1) {
            const int s0 = adj[j];
            const uint4 v0 = ((const uint4*)(xsrc + (size_t)s0 * DIM))[col];
            dot2_acc(a[0], v0.x, SEL_LO); dot2_acc(a[1], v0.x, SEL_HI);
            dot2_acc(a[2], v0.y, SEL_LO); dot2_acc(a[3], v0.y, SEL_HI);
            dot2_acc(a[4], v0.z, SEL_LO); dot2_acc(a[5], v0.z, SEL_HI);
            dot2_acc(a[6], v0.w, SEL_LO); dot2_acc(a[7], v0.w, SEL_HI);
        }
#pragma unroll
        for (int k = 0; k < 8; ++k) a[k] += b[k];
#pragma unroll
        for (int k = 0; k < 8; ++k) {
            a[k] += __shfl_xor(a[k], 8);
            a[k] += __shfl_xor(a[k], 16);
            a[k] += __shfl_xor(a[k], 32);
        }
        if (slot == 0) {
            const float inv = 1.0f / fmaxf((float)(r1 - r0), 1.0f);
            uint4 o;
            o.x = pack_bf2(a[0] * inv, a[1] * inv);
            o.y = pack_bf2(a[2] * inv, a[3] * inv);
            o.z = pack_bf2(a[4] * inv, a[5] * inv);
            o.w = pack_bf2(a[6] * inv, a[7] * inv);
            ((uint4*)(agg + (size_t)(i - n0) * DIM))[col] = o;
        }
    }
}

// ---------------------------------------------------------------------------
// Transform tile: C[64][64] = [agg_bf | xdst_bf][64][128] @ [Wl;Wr][128][64]+b.
// agg bf16 relative n0; xdst bf16 absolute. Outputs fp32 and/or bf16.
// Safe for xdst_b == out_b on the same rows (block stages before storing).
template <int RELU>
__global__ __launch_bounds__(256) void
transform_tile_kernel(const ushort_t* __restrict__ agg,
                      const ushort_t* __restrict__ xdst_b,
                      const float* __restrict__ Wl,
                      const float* __restrict__ Wr,
                      const float* __restrict__ bl,
                      float* __restrict__ out_f,
                      ushort_t* __restrict__ out_b,
                      int n0, int n1) {
    __shared__ float sAX[128 * 64];
    __shared__ float sW[128 * 64];

    const int tid = threadIdx.x;
    {
        const float4* wl4 = (const float4*)Wl;
        const float4* wr4 = (const float4*)Wr;
        float4* sw4 = (float4*)sW;
#pragma unroll
        for (int i = 0; i < 4; ++i) {
            sw4[tid + 256 * i] = wl4[tid + 256 * i];
            sw4[1024 + tid + 256 * i] = wr4[tid + 256 * i];
        }
    }
    const int base = n0 + blockIdx.x * 64;
#pragma unroll
    for (int rep = 0; rep < 4; ++rep) {
        const int idx = rep * 256 + tid;
        const int ln  = idx >> 4;
        const int c   = idx & 15;
        const int node = base + ln;
        const int pc = ((((ln >> 2) ^ c) << 2) | (ln & 3));
        float4 av = make_float4(0.f, 0.f, 0.f, 0.f);
        float4 xv = make_float4(0.f, 0.f, 0.f, 0.f);
        if (node < n1) {
            const uint2 ab = ((const uint2*)(agg + (size_t)(node - n0) * DIM))[c];
            av = make_float4(bf_lo(ab.x), bf_hi(ab.x), bf_lo(ab.y), bf_hi(ab.y));
            const uint2 xb = ((const uint2*)(xdst_b + (size_t)node * DIM))[c];
            xv = make_float4(bf_lo(xb.x), bf_hi(xb.x), bf_lo(xb.y), bf_hi(xb.y));
        }
        sAX[(4 * c + 0) * 64 + pc] = av.x;
        sAX[(4 * c + 1) * 64 + pc] = av.y;
        sAX[(4 * c + 2) * 64 + pc] = av.z;
        sAX[(4 * c + 3) * 64 + pc] = av.w;
        sAX[(64 + 4 * c + 0) * 64 + pc] = xv.x;
        sAX[(64 + 4 * c + 1) * 64 + pc] = xv.y;
        sAX[(64 + 4 * c + 2) * 64 + pc] = xv.z;
        sAX[(64 + 4 * c + 3) * 64 + pc] = xv.w;
    }
    __syncthreads();

    const int rq = tid >> 4;
    const int cq = tid & 15;
    const float4 bv = ((const float4*)bl)[cq];
    float4 a0 = bv, a1 = bv, a2 = bv, a3 = bv;
#pragma unroll 4
    for (int k = 0; k < 128; ++k) {
        const int g = (k >> 2) & 15;
        const float4 av = *(const float4*)&sAX[k * 64 + ((rq ^ g) << 2)];
        const float4 wv = *(const float4*)&sW[k * 64 + (cq << 2)];
        a0.x += av.x * wv.x; a0.y += av.x * wv.y; a0.z += av.x * wv.z; a0.w += av.x * wv.w;
        a1.x += av.y * wv.x; a1.y += av.y * wv.y; a1.z += av.y * wv.z; a1.w += av.y * wv.w;
        a2.x += av.z * wv.x; a2.y += av.z * wv.y; a2.z += av.z * wv.z; a2.w += av.z * wv.w;
        a3.x += av.w * wv.x; a3.y += av.w * wv.y; a3.z += av.w * wv.z; a3.w += av.w * wv.w;
    }
    float4 r[4] = {a0, a1, a2, a3};
#pragma unroll
    for (int i = 0; i < 4; ++i) {
        const int node = base + 4 * rq + i;
        if (node < n1) {
            float4 v = r[i];
            if (RELU) {
                v.x = fmaxf(v.x, 0.f); v.y = fmaxf(v.y, 0.f);
                v.z = fmaxf(v.z, 0.f); v.w = fmaxf(v.w, 0.f);
            }
            if (out_f) ((float4*)(out_f + (size_t)node * DIM))[cq] = v;
            if (out_b)
                ((uint2*)(out_b + (size_t)node * DIM))[cq] =
                    make_uint2(pack_bf2(v.x, v.y), pack_bf2(v.z, v.w));
        }
    }
}

// ---------------------------------------------------------------------------
extern "C" void kernel_launch(void* const* d_in, const int* in_sizes, int n_in,
                              void* d_out, int out_size, void* d_ws, size_t ws_size,
                              hipStream_t stream) {
    const float* x_user  = (const float*)d_in[0];
    const float* x_movie = (const float*)d_in[1];
    const void*  e_src   = d_in[2];
    const void*  e_dst   = d_in[3];
    const float* W1_um_l = (const float*)d_in[4];
    const float* W1_um_r = (const float*)d_in[5];
    const float* W1_mu_l = (const float*)d_in[6];
    const float* W1_mu_r = (const float*)d_in[7];
    const float* W2_um_l = (const float*)d_in[8];
    const float* W2_um_r = (const float*)d_in[9];
    const float* W2_mu_l = (const float*)d_in[10];
    const float* W2_mu_r = (const float*)d_in[11];
    const float* b1_um = (const float*)d_in[12];
    const float* b1_mu = (const float*)d_in[13];
    const float* b2_um = (const float*)d_in[14];
    const float* b2_mu = (const float*)d_in[15];
    const int nE = in_sizes[2];
    const int cpb = (nE + G_SC - 1) / G_SC;

    auto al = [](size_t b) { return (b + 255) & ~(size_t)255; };
    const size_t fixed_b = al(4) + al(((size_t)NU + 1) * 4) + al(((size_t)NM + 1) * 4)
                         + 2 * al((size_t)MBK2 * G_SC * 4) + 2 * al((MBK2 + 1) * 4)
                         + 2 * al((size_t)nE * 4);
    const size_t a1_b = al((size_t)NU * DIM * 2);
    const size_t a2_b = al((size_t)NM * DIM * 2);
    const size_t pair_b = (size_t)2 * nE * 4;
    int CHKr = 50000;
    {
        const int cand[3] = {200000, 100000, 50000};
        for (int k = 0; k < 3; ++k) {
            size_t bphase = (size_t)cand[k] * DIM * 2 + (size_t)NM * DIM * 2 + 1024;
            size_t need = fixed_b + a1_b + a2_b +
                          al(bphase > pair_b ? bphase : pair_b) + 4096;
            if (need <= ws_size) { CHKr = cand[k]; break; }
        }
    }

    char* ws = (char*)d_ws;
    size_t off = 0;
    auto carve = [&](size_t bytes) {
        void* p = ws + off;
        off += al(bytes);
        return p;
    };
    int*      flag     = (int*)carve(4);
    int*      rp_u     = (int*)carve(((size_t)NU + 1) * 4);
    int*      rp_m     = (int*)carve(((size_t)NM + 1) * 4);
    int*      hist_m   = (int*)carve((size_t)MBK2 * G_SC * 4);
    int*      hist_u   = (int*)carve((size_t)MBK2 * G_SC * 4);
    int*      bounds_m = (int*)carve((MBK2 + 1) * 4);
    int*      bounds_u = (int*)carve((MBK2 + 1) * 4);
    int*      adj_u    = (int*)carve((size_t)nE * 4);
    int*      adj_m    = (int*)carve((size_t)nE * 4);
    ushort_t* A1 = (ushort_t*)carve((size_t)NU * DIM * 2);  // xu_bf then u1_bf
    ushort_t* A2 = (ushort_t*)carve((size_t)NM * DIM * 2);  // m1_bf
    size_t bphase = (size_t)CHKr * DIM * 2 + (size_t)NM * DIM * 2 + 1024;
    char*     B      = (char*)carve(bphase > pair_b ? bphase : pair_b);
    unsigned* pr_m   = (unsigned*)B;                        // phase A
    unsigned* pr_u   = (unsigned*)(B + (size_t)nE * 4);     // phase A
    ushort_t* agg_bf = (ushort_t*)B;                        // phase B
    ushort_t* xm_bf  = (ushort_t*)(B + al((size_t)CHKr * DIM * 2)); // phase B
    ushort_t* xu_bf  = A1;
    ushort_t* u1_bf  = A1;
    ushort_t* m1_bf  = A2;

    float* u2 = (float*)d_out;                    // [NU,64]
    float* m2 = (float*)d_out + (size_t)NU * DIM; // [NM,64]

    // ---- build CSR (both directions): radix binning, zero global atomics ----
    detect_idx_kernel<<<1, 256, 0, stream>>>((const unsigned int*)e_src, flag);
    count_kernel<<<G_SC, 256, 0, stream>>>(e_src, e_dst, flag,
                                           hist_m, hist_u, nE, cpb);
    hist_scan_kernel<<<2, 1024, 0, stream>>>(hist_m, hist_u,
                                             bounds_m, bounds_u, nE);
    pair_scatter_kernel<<<G_SC, 256, 0, stream>>>(e_src, e_dst, flag,
                                                  hist_m, hist_u, pr_m, pr_u,
                                                  nE, cpb);
    build_csr_kernel<<<2 * MBK2, 1024, 0, stream>>>(pr_m, pr_u,
                                                    bounds_m, bounds_u,
                                                    rp_m, rp_u, adj_m, adj_u, nE);
    // pr_m/pr_u dead from here; B switches to agg_bf/xm_bf.

    // ---- bf16 source copies (one dispatch) ----
    conv_bf16_kernel<<<2048, 256, 0, stream>>>((const float4*)x_user,
                                               (const float4*)x_movie,
                                               (uint2*)xu_bf, (uint2*)xm_bf);

    auto run_dir = [&](const ushort_t* src_bf, const int* rp, const int* adj,
                       const ushort_t* xdst_bf, const float* Wl, const float* Wr,
                       const float* bl, float* outf, ushort_t* outb,
                       int n_tot, int relu) {
        for (int n0 = 0; n0 < n_tot; n0 += CHKr) {
            const int n1 = min(n_tot, n0 + CHKr);
            const int gb = (n1 - n0 + 3) / 4;       // 1 node/wave
            const int tb = (n1 - n0 + 63) / 64;
            gather_mean_bf16_kernel<<<gb, 256, 0, stream>>>(src_bf, rp, adj,
                                                            agg_bf, n0, n1);
            if (relu)
                transform_tile_kernel<1><<<tb, 256, 0, stream>>>(agg_bf, xdst_bf,
                    Wl, Wr, bl, outf, outb, n0, n1);
            else
                transform_tile_kernel<0><<<tb, 256, 0, stream>>>(agg_bf, xdst_bf,
                    Wl, Wr, bl, outf, outb, n0, n1);
        }
    };

    // ---- layer 1 (bf16 intermediates only) ----
    run_dir(xu_bf, rp_m, adj_m, xm_bf, W1_um_l, W1_um_r, b1_um,
            nullptr, m1_bf, NM, 1);
    run_dir(xm_bf, rp_u, adj_u, xu_bf, W1_mu_l, W1_mu_r, b1_mu,
            nullptr, u1_bf, NU, 1);
    // ---- layer 2 (fp32 outputs straight to d_out) ----
    run_dir(u1_bf, rp_m, adj_m, m1_bf, W2_um_l, W2_um_r, b2_um,
            m2, nullptr, NM, 0);
    run_dir(m1_bf, rp_u, adj_u, u1_bf, W2_mu_l, W2_mu_r, b2_mu,
            u2, nullptr, NU, 0);
}

// Round 13
// 423.512 us; speedup vs baseline: 1.5657x; 1.2612x over previous
//
#include <hip/hip_runtime.h>
#include <stdint.h>

#define NU 200000
#define NM 100000
#define DIM 64
#define MBK2 64          // buckets per direction
#define SP_M 1563        // movie node span per bucket (ceil(NM/64))
#define SP_U 3125        // user  node span per bucket (NU/64)
#define G_SC 1024        // blocks for count/pair_scatter (fixed chunk assignment)

typedef unsigned short ushort_t;
typedef __attribute__((ext_vector_type(8))) short bf16x8;
typedef __attribute__((ext_vector_type(4))) float f32x4;

// ---------------------------------------------------------------------------
// bf16 helpers (RNE)
__device__ __forceinline__ unsigned pack_bf2(float lo, float hi) {
    unsigned ul = __float_as_uint(lo); ul += 0x7fffu + ((ul >> 16) & 1u);
    unsigned uh = __float_as_uint(hi); uh += 0x7fffu + ((uh >> 16) & 1u);
    return (ul >> 16) | (uh & 0xffff0000u);
}
__device__ __forceinline__ ushort_t pack_bf1(float v) {
    unsigned u = __float_as_uint(v); u += 0x7fffu + ((u >> 16) & 1u);
    return (ushort_t)(u >> 16);
}
__device__ __forceinline__ float bf_lo(unsigned u) { return __uint_as_float(u << 16); }
__device__ __forceinline__ float bf_hi(unsigned u) { return __uint_as_float(u & 0xffff0000u); }

// v_dot2_f32_bf16: acc += pair.lo*sel.lo + pair.hi*sel.hi (1 VALU op)
__device__ __forceinline__ void dot2_acc(float& acc, unsigned pair, unsigned sel) {
    asm("v_dot2_f32_bf16 %0, %1, %2, %0" : "+v"(acc) : "v"(pair), "v"(sel));
}

// ---------------------------------------------------------------------------
// Detect whether edge index arrays are int64 or int32.
__global__ void detect_idx_kernel(const unsigned int* __restrict__ words,
                                  int* __restrict__ flag) {
    __shared__ int nz;
    if (threadIdx.x == 0) nz = 0;
    __syncthreads();
    for (int i = threadIdx.x; i < 2048; i += blockDim.x)
        if (words[2 * i + 1] != 0u) nz = 1;
    __syncthreads();
    if (threadIdx.x == 0) *flag = (nz == 0) ? 1 : 0;   // 1 => int64
}

__device__ __forceinline__ int load_idx(const void* __restrict__ p, int e, int is64) {
    if (is64) return (int)((const long long*)p)[e];
    return ((const int*)p)[e];
}

// ---------------------------------------------------------------------------
// fp32 -> bf16 (RNE) for BOTH feature tables in one dispatch.
__global__ void conv_bf16_kernel(const float4* __restrict__ xu,
                                 const float4* __restrict__ xm,
                                 uint2* __restrict__ xu_bf,
                                 uint2* __restrict__ xm_bf) {
    const int nu4 = NU * 16, nm4 = NM * 16;
    const int stride = gridDim.x * blockDim.x;
    for (int i = blockIdx.x * blockDim.x + threadIdx.x; i < nu4 + nm4; i += stride) {
        if (i < nu4) {
            const float4 v = xu[i];
            xu_bf[i] = make_uint2(pack_bf2(v.x, v.y), pack_bf2(v.z, v.w));
        } else {
            const float4 v = xm[i - nu4];
            xm_bf[i - nu4] = make_uint2(pack_bf2(v.x, v.y), pack_bf2(v.z, v.w));
        }
    }
}

// ---------------------------------------------------------------------------
// Weight prep: 4 direction-layer tables -> wt[tbl][n][k] bf16 (k-contiguous,
// k<64 = Wl[k][n], k>=64 = Wr[k-64][n]).  4 x 8192 bf16 = 64KB.
__global__ void prep_w_kernel(const float* __restrict__ W1ml, const float* __restrict__ W1mr,
                              const float* __restrict__ W1ul, const float* __restrict__ W1ur,
                              const float* __restrict__ W2ml, const float* __restrict__ W2mr,
                              const float* __restrict__ W2ul, const float* __restrict__ W2ur,
                              ushort_t* __restrict__ wt) {
    const int t = blockIdx.x * blockDim.x + threadIdx.x;
    if (t >= 4 * 8192) return;
    const int tbl = t >> 13, r = t & 8191;
    const int n = r >> 7, k = r & 127;
    const float* Wl; const float* Wr;
    switch (tbl) {
        case 0:  Wl = W1ml; Wr = W1mr; break;
        case 1:  Wl = W1ul; Wr = W1ur; break;
        case 2:  Wl = W2ml; Wr = W2mr; break;
        default: Wl = W2ul; Wr = W2ur; break;
    }
    const float v = (k < 64) ? Wl[k * 64 + n] : Wr[(k - 64) * 64 + n];
    wt[t] = pack_bf1(v);
}

// ---------------------------------------------------------------------------
// Per-block 64-bucket histograms, both directions (bucket-major layout
// hist[b*G_SC + blk]); FIXED per-block edge chunks.
__global__ void count_kernel(const void* __restrict__ es, const void* __restrict__ ed,
                             const int* __restrict__ flag,
                             int* __restrict__ hist_m, int* __restrict__ hist_u,
                             int nE, int cpb) {
    __shared__ int h[2 * MBK2];
    if (threadIdx.x < 2 * MBK2) h[threadIdx.x] = 0;
    __syncthreads();
    const int is64 = *flag;
    const int e0 = blockIdx.x * cpb;
    const int e1 = min(nE, e0 + cpb);
    for (int e = e0 + threadIdx.x; e < e1; e += blockDim.x) {
        int s = load_idx(es, e, is64);
        int d = load_idx(ed, e, is64);
        atomicAdd(&h[(unsigned)d / SP_M], 1);
        atomicAdd(&h[MBK2 + (unsigned)s / SP_U], 1);
    }
    __syncthreads();
    if (threadIdx.x < MBK2)
        hist_m[threadIdx.x * G_SC + blockIdx.x] = h[threadIdx.x];
    else if (threadIdx.x < 2 * MBK2)
        hist_u[(threadIdx.x - MBK2) * G_SC + blockIdx.x] = h[threadIdx.x];
}

// ---------------------------------------------------------------------------
// Exclusive scan of per-block bucket histogram (64*G_SC, bucket-major) in
// place; emits bounds[0..64]. 2 blocks (movie, user).
__global__ __launch_bounds__(1024) void
hist_scan_kernel(int* __restrict__ hist_m, int* __restrict__ hist_u,
                 int* __restrict__ bounds_m, int* __restrict__ bounds_u, int nE) {
    int* hist   = (blockIdx.x == 0) ? hist_m : hist_u;
    int* bounds = (blockIdx.x == 0) ? bounds_m : bounds_u;
    const int t = threadIdx.x;          // 1024 threads x 64 = 64*G_SC
    const int base = t * 64;
    int v[64];
    int tot = 0;
#pragma unroll
    for (int k = 0; k < 64; ++k) { v[k] = hist[base + k]; tot += v[k]; }
    __shared__ int sc[1024];
    sc[t] = tot;
    __syncthreads();
    for (int off = 1; off < 1024; off <<= 1) {
        int x = (t >= off) ? sc[t - off] : 0;
        __syncthreads();
        sc[t] += x;
        __syncthreads();
    }
    int excl = sc[t] - tot;
#pragma unroll
    for (int k = 0; k < 64; ++k) { int tmp = v[k]; hist[base + k] = excl; excl += tmp; }
    __syncthreads();
    if (t < MBK2) bounds[t] = hist[t * G_SC];
    else if (t == MBK2) bounds[MBK2] = nE;
}

// ---------------------------------------------------------------------------
// Level-1 scatter, deterministic (LDS cursors, exclusive per-bucket chunks).
__global__ void pair_scatter_kernel(const void* __restrict__ es,
                                    const void* __restrict__ ed,
                                    const int* __restrict__ flag,
                                    const int* __restrict__ hist_m,
                                    const int* __restrict__ hist_u,
                                    unsigned* __restrict__ pr_m,
                                    unsigned* __restrict__ pr_u,
                                    int nE, int cpb) {
    __shared__ int cur[2 * MBK2];
    if (threadIdx.x < MBK2)
        cur[threadIdx.x] = hist_m[threadIdx.x * G_SC + blockIdx.x];
    else if (threadIdx.x < 2 * MBK2)
        cur[threadIdx.x] = hist_u[(threadIdx.x - MBK2) * G_SC + blockIdx.x];
    __syncthreads();
    const int is64 = *flag;
    const int e0 = blockIdx.x * cpb;
    const int e1 = min(nE, e0 + cpb);
    for (int e = e0 + threadIdx.x; e < e1; e += blockDim.x) {
        const int s = load_idx(es, e, is64);
        const int d = load_idx(ed, e, is64);
        const int b0 = (unsigned)d / SP_M;
        const int b1 = (unsigned)s / SP_U;
        const int p0 = atomicAdd(&cur[b0], 1);
        pr_m[p0] = ((unsigned)(d - b0 * SP_M) << 18) | (unsigned)s;
        const int p1 = atomicAdd(&cur[MBK2 + b1], 1);
        pr_u[p1] = ((unsigned)(s - b1 * SP_U) << 17) | (unsigned)d;
    }
}

// ---------------------------------------------------------------------------
// Merged CSR build: ONE block per bucket (LDS degree hist -> LDS scan ->
// rowptr write -> adj fill into XCD-exclusive region).
__global__ __launch_bounds__(1024) void
build_csr_kernel(const unsigned* __restrict__ pr_m, const unsigned* __restrict__ pr_u,
                 const int* __restrict__ bounds_m, const int* __restrict__ bounds_u,
                 int* __restrict__ rp_m, int* __restrict__ rp_u,
                 int* __restrict__ adj_m, int* __restrict__ adj_u, int nE) {
    __shared__ int cur[SP_U];
    __shared__ int ps[1024];
    const int t = threadIdx.x;
    const int b = blockIdx.x;
    const bool mv = (b < MBK2);
    const int bb = mv ? b : b - MBK2;
    const int span  = mv ? SP_M : SP_U;
    const int shift = mv ? 18 : 17;
    const unsigned mask = (1u << shift) - 1u;
    const unsigned* pr = mv ? pr_m : pr_u;
    const int* bounds  = mv ? bounds_m : bounds_u;
    int* rp  = mv ? rp_m : rp_u;
    int* adj = mv ? adj_m : adj_u;
    const int n_tot = mv ? NM : NU;
    const int nb = bb * span;
    const int s0 = bounds[bb], s1 = bounds[bb + 1];

    for (int i = t; i < span; i += 1024) cur[i] = 0;
    __syncthreads();
    for (int i = s0 + t; i < s1; i += 1024)
        atomicAdd(&cur[pr[i] >> shift], 1);
    __syncthreads();
    int v[4];
    int loc = 0;
#pragma unroll
    for (int k = 0; k < 4; ++k) {
        const int i = t * 4 + k;
        v[k] = (i < span) ? cur[i] : 0;
        loc += v[k];
    }
    ps[t] = loc;
    __syncthreads();
    for (int off = 1; off < 1024; off <<= 1) {
        int x = (t >= off) ? ps[t - off] : 0;
        __syncthreads();
        ps[t] += x;
        __syncthreads();
    }
    int run = s0 + ps[t] - loc;
#pragma unroll
    for (int k = 0; k < 4; ++k) {
        const int i = t * 4 + k;
        if (i < span) {
            if (nb + i < n_tot) rp[nb + i] = run;
            cur[i] = run;
            run += v[k];
        }
    }
    if (bb == MBK2 - 1 && t == 0) rp[n_tot] = nE;   // sentinel
    __syncthreads();
    for (int i = s0 + t; i < s1; i += 1024) {
        const unsigned w = pr[i];
        const int slot = atomicAdd(&cur[w >> shift], 1);
        adj[slot] = (int)(w & mask);
    }
}

// ---------------------------------------------------------------------------
// bf16 mean-aggregate gather (unchanged; dot2 accumulate).
__global__ __launch_bounds__(256) void
gather_mean_bf16_kernel(const ushort_t* __restrict__ xsrc,
                        const int* __restrict__ rowptr,
                        const int* __restrict__ adj,
                        ushort_t* __restrict__ agg,
                        int n0, int n1) {
    const unsigned SEL_LO = 0x00003f80u;   // bf16 (1.0, 0)
    const unsigned SEL_HI = 0x3f800000u;   // bf16 (0, 1.0)
    const int lane = threadIdx.x & 63;
    const int slot = lane >> 3;
    const int col  = lane & 7;
    const int wid  = (blockIdx.x * blockDim.x + threadIdx.x) >> 6;
    const int nw   = (gridDim.x * blockDim.x) >> 6;
    for (int i = n0 + wid; i < n1; i += nw) {
        const int r0 = rowptr[i], r1 = rowptr[i + 1];
        float a[8] = {0.f, 0.f, 0.f, 0.f, 0.f, 0.f, 0.f, 0.f};
        float b[8] = {0.f, 0.f, 0.f, 0.f, 0.f, 0.f, 0.f, 0.f};
        int j = r0 + slot;
        for (; j + 8 < r1; j += 16) {
            const int s0 = adj[j];
            const int s1 = adj[j + 8];
            const uint4 v0 = ((const uint4*)(xsrc + (size_t)s0 * DIM))[col];
            const uint4 v1 = ((const uint4*)(xsrc + (size_t)s1 * DIM))[col];
            dot2_acc(a[0], v0.x, SEL_LO); dot2_acc(a[1], v0.x, SEL_HI);
            dot2_acc(a[2], v0.y, SEL_LO); dot2_acc(a[3], v0.y, SEL_HI);
            dot2_acc(a[4], v0.z, SEL_LO); dot2_acc(a[5], v0.z, SEL_HI);
            dot2_acc(a[6], v0.w, SEL_LO); dot2_acc(a[7], v0.w, SEL_HI);
            dot2_acc(b[0], v1.x, SEL_LO); dot2_acc(b[1], v1.x, SEL_HI);
            dot2_acc(b[2], v1.y, SEL_LO); dot2_acc(b[3], v1.y, SEL_HI);
            dot2_acc(b[4], v1.z, SEL_LO); dot2_acc(b[5], v1.z, SEL_HI);
            dot2_acc(b[6], v1.w, SEL_LO); dot2_acc(b[7], v1.w, SEL_HI);
        }
        if (j < r1) {
            const int s0 = adj[j];
            const uint4 v0 = ((const uint4*)(xsrc + (size_t)s0 * DIM))[col];
            dot2_acc(a[0], v0.x, SEL_LO); dot2_acc(a[1], v0.x, SEL_HI);
            dot2_acc(a[2], v0.y, SEL_LO); dot2_acc(a[3], v0.y, SEL_HI);
            dot2_acc(a[4], v0.z, SEL_LO); dot2_acc(a[5], v0.z, SEL_HI);
            dot2_acc(a[6], v0.w, SEL_LO); dot2_acc(a[7], v0.w, SEL_HI);
        }
#pragma unroll
        for (int k = 0; k < 8; ++k) a[k] += b[k];
#pragma unroll
        for (int k = 0; k < 8; ++k) {
            a[k] += __shfl_xor(a[k], 8);
            a[k] += __shfl_xor(a[k], 16);
            a[k] += __shfl_xor(a[k], 32);
        }
        if (slot == 0) {
            const float inv = 1.0f / fmaxf((float)(r1 - r0), 1.0f);
            uint4 o;
            o.x = pack_bf2(a[0] * inv, a[1] * inv);
            o.y = pack_bf2(a[2] * inv, a[3] * inv);
            o.z = pack_bf2(a[4] * inv, a[5] * inv);
            o.w = pack_bf2(a[6] * inv, a[7] * inv);
            ((uint4*)(agg + (size_t)(i - n0) * DIM))[col] = o;
        }
    }
}

// ---------------------------------------------------------------------------
// MFMA transform: C[64 nodes][64 dims] = A[64][128] @ W[128][64] + b,
// A = [agg | xdst] bf16, W pre-transposed bf16 (wt[n][k], k-contiguous).
// mfma_f32_16x16x32_bf16: A-frag lane l holds A[m=l&15][k=(l>>4)*8..+7];
// B-frag lane l holds W[k=(l>>4)*8..+7][n=l&15] (read from wt[n][k] rows);
// C/D: col=lane&15, row=(lane>>4)*4+reg [verified mapping].
// LDS rows are 256B -> granule-XOR swizzle (g ^= row&15) keeps b128 reads
// at worst 2-way bank aliased (free).
template <int RELU>
__global__ __launch_bounds__(256) void
transform_mfma_kernel(const ushort_t* __restrict__ agg,
                      const ushort_t* __restrict__ xdst_b,
                      const ushort_t* __restrict__ wt,
                      const float* __restrict__ bl,
                      float* __restrict__ out_f,
                      ushort_t* __restrict__ out_b,
                      int n0, int n1) {
    __shared__ ushort_t sA[64 * 128];   // 16KB, swizzled granules
    __shared__ ushort_t sB[64 * 128];   // 16KB, swizzled granules

    const int tid = threadIdx.x;
    const int base = n0 + blockIdx.x * 64;
    // stage sB from wt (1024 uint4, coalesced; swizzle granule per row)
    {
        const uint4* w4 = (const uint4*)wt;
#pragma unroll
        for (int i = 0; i < 4; ++i) {
            const int idx = i * 256 + tid;        // 0..1023
            const int row = idx >> 4;             // n
            const int g   = idx & 15;             // granule (8 bf16)
            ((uint4*)sB)[row * 16 + (g ^ (row & 15))] = w4[idx];
        }
    }
    // stage sA: row ln = [agg(node) | xdst(node)]; 1024 uint4
#pragma unroll
    for (int i = 0; i < 4; ++i) {
        const int idx = i * 256 + tid;
        const int ln   = idx >> 4;                // node local 0..63
        const int g    = idx & 15;                // granule: 0-7 agg, 8-15 xdst
        const int node = base + ln;
        uint4 v = make_uint4(0, 0, 0, 0);
        if (node < n1)
            v = (g < 8) ? ((const uint4*)(agg + (size_t)(node - n0) * DIM))[g]
                        : ((const uint4*)(xdst_b + (size_t)node * DIM))[g - 8];
        ((uint4*)sA)[ln * 16 + (g ^ (ln & 15))] = v;
    }
    __syncthreads();

    const int w    = tid >> 6;       // wave 0..3 -> node rows w*16..+15
    const int lane = tid & 63;
    const int m    = lane & 15;
    const int kg   = lane >> 4;      // k-group (8 bf16 each)
    f32x4 acc0 = {0.f, 0.f, 0.f, 0.f}, acc1 = acc0, acc2 = acc0, acc3 = acc0;
    const int ar = w * 16 + m;       // A row
#pragma unroll
    for (int kk = 0; kk < 4; ++kk) {
        const int g = kk * 4 + kg;   // granule index of this fragment's 8 k
        const bf16x8 afr = ((const bf16x8*)sA)[ar * 16 + (g ^ (ar & 15))];
        {
            const int br = m;        // n row 0..15
            const bf16x8 bfr = ((const bf16x8*)sB)[br * 16 + (g ^ (br & 15))];
            acc0 = __builtin_amdgcn_mfma_f32_16x16x32_bf16(afr, bfr, acc0, 0, 0, 0);
        }
        {
            const int br = 16 + m;
            const bf16x8 bfr = ((const bf16x8*)sB)[br * 16 + (g ^ (br & 15))];
            acc1 = __builtin_amdgcn_mfma_f32_16x16x32_bf16(afr, bfr, acc1, 0, 0, 0);
        }
        {
            const int br = 32 + m;
            const bf16x8 bfr = ((const bf16x8*)sB)[br * 16 + (g ^ (br & 15))];
            acc2 = __builtin_amdgcn_mfma_f32_16x16x32_bf16(afr, bfr, acc2, 0, 0, 0);
        }
        {
            const int br = 48 + m;
            const bf16x8 bfr = ((const bf16x8*)sB)[br * 16 + (g ^ (br & 15))];
            acc3 = __builtin_amdgcn_mfma_f32_16x16x32_bf16(afr, bfr, acc3, 0, 0, 0);
        }
    }
    // epilogue: D col=lane&15, row=(lane>>4)*4+reg
    const int col = lane & 15;
    const int rb  = (lane >> 4) * 4;
    f32x4 av[4] = {acc0, acc1, acc2, acc3};
#pragma unroll
    for (int ni = 0; ni < 4; ++ni) {
        const int n = ni * 16 + col;
        const float bias = bl[n];
#pragma unroll
        for (int r = 0; r < 4; ++r) {
            const int node = base + w * 16 + rb + r;
            if (node < n1) {
                float v = av[ni][r] + bias;
                if (RELU) v = fmaxf(v, 0.f);
                if (out_f) out_f[(size_t)node * DIM + n] = v;
                if (out_b) out_b[(size_t)node * DIM + n] = pack_bf1(v);
            }
        }
    }
}

// ---------------------------------------------------------------------------
extern "C" void kernel_launch(void* const* d_in, const int* in_sizes, int n_in,
                              void* d_out, int out_size, void* d_ws, size_t ws_size,
                              hipStream_t stream) {
    const float* x_user  = (const float*)d_in[0];
    const float* x_movie = (const float*)d_in[1];
    const void*  e_src   = d_in[2];
    const void*  e_dst   = d_in[3];
    const float* W1_um_l = (const float*)d_in[4];
    const float* W1_um_r = (const float*)d_in[5];
    const float* W1_mu_l = (const float*)d_in[6];
    const float* W1_mu_r = (const float*)d_in[7];
    const float* W2_um_l = (const float*)d_in[8];
    const float* W2_um_r = (const float*)d_in[9];
    const float* W2_mu_l = (const float*)d_in[10];
    const float* W2_mu_r = (const float*)d_in[11];
    const float* b1_um = (const float*)d_in[12];
    const float* b1_mu = (const float*)d_in[13];
    const float* b2_um = (const float*)d_in[14];
    const float* b2_mu = (const float*)d_in[15];
    const int nE = in_sizes[2];
    const int cpb = (nE + G_SC - 1) / G_SC;

    auto al = [](size_t b) { return (b + 255) & ~(size_t)255; };
    const size_t fixed_b = al(4) + al(((size_t)NU + 1) * 4) + al(((size_t)NM + 1) * 4)
                         + 2 * al((size_t)MBK2 * G_SC * 4) + 2 * al((MBK2 + 1) * 4)
                         + 2 * al((size_t)nE * 4) + al(4 * 8192 * 2);
    const size_t a1_b = al((size_t)NU * DIM * 2);
    const size_t a2_b = al((size_t)NM * DIM * 2);
    const size_t pair_b = (size_t)2 * nE * 4;
    int CHKr = 50000;
    {
        const int cand[3] = {200000, 100000, 50000};
        for (int k = 0; k < 3; ++k) {
            size_t bphase = (size_t)cand[k] * DIM * 2 + (size_t)NM * DIM * 2 + 1024;
            size_t need = fixed_b + a1_b + a2_b +
                          al(bphase > pair_b ? bphase : pair_b) + 4096;
            if (need <= ws_size) { CHKr = cand[k]; break; }
        }
    }

    char* ws = (char*)d_ws;
    size_t off = 0;
    auto carve = [&](size_t bytes) {
        void* p = ws + off;
        off += al(bytes);
        return p;
    };
    int*      flag     = (int*)carve(4);
    int*      rp_u     = (int*)carve(((size_t)NU + 1) * 4);
    int*      rp_m     = (int*)carve(((size_t)NM + 1) * 4);
    int*      hist_m   = (int*)carve((size_t)MBK2 * G_SC * 4);
    int*      hist_u   = (int*)carve((size_t)MBK2 * G_SC * 4);
    int*      bounds_m = (int*)carve((MBK2 + 1) * 4);
    int*      bounds_u = (int*)carve((MBK2 + 1) * 4);
    int*      adj_u    = (int*)carve((size_t)nE * 4);
    int*      adj_m    = (int*)carve((size_t)nE * 4);
    ushort_t* wt_all   = (ushort_t*)carve(4 * 8192 * 2);    // 4 x [64][128] bf16
    ushort_t* A1 = (ushort_t*)carve((size_t)NU * DIM * 2);  // xu_bf then u1_bf
    ushort_t* A2 = (ushort_t*)carve((size_t)NM * DIM * 2);  // m1_bf
    size_t bphase = (size_t)CHKr * DIM * 2 + (size_t)NM * DIM * 2 + 1024;
    char*     B      = (char*)carve(bphase > pair_b ? bphase : pair_b);
    unsigned* pr_m   = (unsigned*)B;                        // phase A
    unsigned* pr_u   = (unsigned*)(B + (size_t)nE * 4);     // phase A
    ushort_t* agg_bf = (ushort_t*)B;                        // phase B
    ushort_t* xm_bf  = (ushort_t*)(B + al((size_t)CHKr * DIM * 2)); // phase B
    ushort_t* xu_bf  = A1;
    ushort_t* u1_bf  = A1;
    ushort_t* m1_bf  = A2;
    ushort_t* wt1m = wt_all;            // layer1 movie (W1_um)
    ushort_t* wt1u = wt_all + 8192;     // layer1 user  (W1_mu)
    ushort_t* wt2m = wt_all + 16384;    // layer2 movie (W2_um)
    ushort_t* wt2u = wt_all + 24576;    // layer2 user  (W2_mu)

    float* u2 = (float*)d_out;                    // [NU,64]
    float* m2 = (float*)d_out + (size_t)NU * DIM; // [NM,64]

    // ---- build CSR (both directions): radix binning, zero global atomics ----
    detect_idx_kernel<<<1, 256, 0, stream>>>((const unsigned int*)e_src, flag);
    count_kernel<<<G_SC, 256, 0, stream>>>(e_src, e_dst, flag,
                                           hist_m, hist_u, nE, cpb);
    hist_scan_kernel<<<2, 1024, 0, stream>>>(hist_m, hist_u,
                                             bounds_m, bounds_u, nE);
    pair_scatter_kernel<<<G_SC, 256, 0, stream>>>(e_src, e_dst, flag,
                                                  hist_m, hist_u, pr_m, pr_u,
                                                  nE, cpb);
    build_csr_kernel<<<2 * MBK2, 1024, 0, stream>>>(pr_m, pr_u,
                                                    bounds_m, bounds_u,
                                                    rp_m, rp_u, adj_m, adj_u, nE);
    // pr_m/pr_u dead from here; B switches to agg_bf/xm_bf.

    // ---- bf16 sources + transposed bf16 weights ----
    conv_bf16_kernel<<<2048, 256, 0, stream>>>((const float4*)x_user,
                                               (const float4*)x_movie,
                                               (uint2*)xu_bf, (uint2*)xm_bf);
    prep_w_kernel<<<128, 256, 0, stream>>>(W1_um_l, W1_um_r, W1_mu_l, W1_mu_r,
                                           W2_um_l, W2_um_r, W2_mu_l, W2_mu_r,
                                           wt_all);

    auto run_dir = [&](const ushort_t* src_bf, const int* rp, const int* adj,
                       const ushort_t* xdst_bf, const ushort_t* wt,
                       const float* bl, float* outf, ushort_t* outb,
                       int n_tot, int relu) {
        for (int n0 = 0; n0 < n_tot; n0 += CHKr) {
            const int n1 = min(n_tot, n0 + CHKr);
            const int gb = (n1 - n0 + 3) / 4;       // 1 node/wave
            const int tb = (n1 - n0 + 63) / 64;
            gather_mean_bf16_kernel<<<gb, 256, 0, stream>>>(src_bf, rp, adj,
                                                            agg_bf, n0, n1);
            if (relu)
                transform_mfma_kernel<1><<<tb, 256, 0, stream>>>(agg_bf, xdst_bf,
                    wt, bl, outf, outb, n0, n1);
            else
                transform_mfma_kernel<0><<<tb, 256, 0, stream>>>(agg_bf, xdst_bf,
                    wt, bl, outf, outb, n0, n1);
        }
    };

    // ---- layer 1 (bf16 intermediates only) ----
    run_dir(xu_bf, rp_m, adj_m, xm_bf, wt1m, b1_um, nullptr, m1_bf, NM, 1);
    run_dir(xm_bf, rp_u, adj_u, xu_bf, wt1u, b1_mu, nullptr, u1_bf, NU, 1);
    // ---- layer 2 (fp32 outputs straight to d_out) ----
    run_dir(u1_bf, rp_m, adj_m, m1_bf, wt2m, b2_um, m2, nullptr, NM, 0);
    run_dir(m1_bf, rp_u, adj_u, u1_bf, wt2u, b2_mu, u2, nullptr, NU, 0);
}

// Round 14
// 351.372 us; speedup vs baseline: 1.8871x; 1.2053x over previous
//
#include <hip/hip_runtime.h>
#include <stdint.h>

#define NU 200000
#define NM 100000
#define DIM 64
#define MBK2 64          // buckets per direction
#define SP_M 1563        // movie node span per bucket (ceil(NM/64))
#define SP_U 3125        // user  node span per bucket (NU/64)
#define G_SC 1024        // blocks for count/pair_scatter (fixed chunk assignment)

typedef unsigned short ushort_t;
typedef __attribute__((ext_vector_type(8))) short bf16x8;
typedef __attribute__((ext_vector_type(4))) float f32x4;

// ---------------------------------------------------------------------------
// bf16 helpers (RNE)
__device__ __forceinline__ unsigned pack_bf2(float lo, float hi) {
    unsigned ul = __float_as_uint(lo); ul += 0x7fffu + ((ul >> 16) & 1u);
    unsigned uh = __float_as_uint(hi); uh += 0x7fffu + ((uh >> 16) & 1u);
    return (ul >> 16) | (uh & 0xffff0000u);
}
__device__ __forceinline__ ushort_t pack_bf1(float v) {
    unsigned u = __float_as_uint(v); u += 0x7fffu + ((u >> 16) & 1u);
    return (ushort_t)(u >> 16);
}
__device__ __forceinline__ float bf_lo(unsigned u) { return __uint_as_float(u << 16); }
__device__ __forceinline__ float bf_hi(unsigned u) { return __uint_as_float(u & 0xffff0000u); }

// v_dot2_f32_bf16: acc += pair.lo*sel.lo + pair.hi*sel.hi (1 VALU op)
__device__ __forceinline__ void dot2_acc(float& acc, unsigned pair, unsigned sel) {
    asm("v_dot2_f32_bf16 %0, %1, %2, %0" : "+v"(acc) : "v"(pair), "v"(sel));
}
__device__ __forceinline__ void acc8(float* a, const uint4& v,
                                     unsigned SEL_LO, unsigned SEL_HI) {
    dot2_acc(a[0], v.x, SEL_LO); dot2_acc(a[1], v.x, SEL_HI);
    dot2_acc(a[2], v.y, SEL_LO); dot2_acc(a[3], v.y, SEL_HI);
    dot2_acc(a[4], v.z, SEL_LO); dot2_acc(a[5], v.z, SEL_HI);
    dot2_acc(a[6], v.w, SEL_LO); dot2_acc(a[7], v.w, SEL_HI);
}

// ---------------------------------------------------------------------------
// Detect whether edge index arrays are int64 or int32.
__global__ void detect_idx_kernel(const unsigned int* __restrict__ words,
                                  int* __restrict__ flag) {
    __shared__ int nz;
    if (threadIdx.x == 0) nz = 0;
    __syncthreads();
    for (int i = threadIdx.x; i < 2048; i += blockDim.x)
        if (words[2 * i + 1] != 0u) nz = 1;
    __syncthreads();
    if (threadIdx.x == 0) *flag = (nz == 0) ? 1 : 0;   // 1 => int64
}

__device__ __forceinline__ int load_idx(const void* __restrict__ p, int e, int is64) {
    if (is64) return (int)((const long long*)p)[e];
    return ((const int*)p)[e];
}

// ---------------------------------------------------------------------------
// fp32 -> bf16 (RNE) for BOTH feature tables in one dispatch.
__global__ void conv_bf16_kernel(const float4* __restrict__ xu,
                                 const float4* __restrict__ xm,
                                 uint2* __restrict__ xu_bf,
                                 uint2* __restrict__ xm_bf) {
    const int nu4 = NU * 16, nm4 = NM * 16;
    const int stride = gridDim.x * blockDim.x;
    for (int i = blockIdx.x * blockDim.x + threadIdx.x; i < nu4 + nm4; i += stride) {
        if (i < nu4) {
            const float4 v = xu[i];
            xu_bf[i] = make_uint2(pack_bf2(v.x, v.y), pack_bf2(v.z, v.w));
        } else {
            const float4 v = xm[i - nu4];
            xm_bf[i - nu4] = make_uint2(pack_bf2(v.x, v.y), pack_bf2(v.z, v.w));
        }
    }
}

// ---------------------------------------------------------------------------
// Weight prep: 4 direction-layer tables -> wt[tbl][n][k] bf16 (k-contiguous,
// k<64 = Wl[k][n], k>=64 = Wr[k-64][n]).  4 x 8192 bf16 = 64KB.
__global__ void prep_w_kernel(const float* __restrict__ W1ml, const float* __restrict__ W1mr,
                              const float* __restrict__ W1ul, const float* __restrict__ W1ur,
                              const float* __restrict__ W2ml, const float* __restrict__ W2mr,
                              const float* __restrict__ W2ul, const float* __restrict__ W2ur,
                              ushort_t* __restrict__ wt) {
    const int t = blockIdx.x * blockDim.x + threadIdx.x;
    if (t >= 4 * 8192) return;
    const int tbl = t >> 13, r = t & 8191;
    const int n = r >> 7, k = r & 127;
    const float* Wl; const float* Wr;
    switch (tbl) {
        case 0:  Wl = W1ml; Wr = W1mr; break;
        case 1:  Wl = W1ul; Wr = W1ur; break;
        case 2:  Wl = W2ml; Wr = W2mr; break;
        default: Wl = W2ul; Wr = W2ur; break;
    }
    const float v = (k < 64) ? Wl[k * 64 + n] : Wr[(k - 64) * 64 + n];
    wt[t] = pack_bf1(v);
}

// ---------------------------------------------------------------------------
// Per-block 64-bucket histograms, both directions (bucket-major layout
// hist[b*G_SC + blk]); FIXED per-block edge chunks.
__global__ void count_kernel(const void* __restrict__ es, const void* __restrict__ ed,
                             const int* __restrict__ flag,
                             int* __restrict__ hist_m, int* __restrict__ hist_u,
                             int nE, int cpb) {
    __shared__ int h[2 * MBK2];
    if (threadIdx.x < 2 * MBK2) h[threadIdx.x] = 0;
    __syncthreads();
    const int is64 = *flag;
    const int e0 = blockIdx.x * cpb;
    const int e1 = min(nE, e0 + cpb);
    for (int e = e0 + threadIdx.x; e < e1; e += blockDim.x) {
        int s = load_idx(es, e, is64);
        int d = load_idx(ed, e, is64);
        atomicAdd(&h[(unsigned)d / SP_M], 1);
        atomicAdd(&h[MBK2 + (unsigned)s / SP_U], 1);
    }
    __syncthreads();
    if (threadIdx.x < MBK2)
        hist_m[threadIdx.x * G_SC + blockIdx.x] = h[threadIdx.x];
    else if (threadIdx.x < 2 * MBK2)
        hist_u[(threadIdx.x - MBK2) * G_SC + blockIdx.x] = h[threadIdx.x];
}

// ---------------------------------------------------------------------------
// Exclusive scan of per-block bucket histogram (64*G_SC, bucket-major) in
// place; emits bounds[0..64]. 2 blocks (movie, user).
__global__ __launch_bounds__(1024) void
hist_scan_kernel(int* __restrict__ hist_m, int* __restrict__ hist_u,
                 int* __restrict__ bounds_m, int* __restrict__ bounds_u, int nE) {
    int* hist   = (blockIdx.x == 0) ? hist_m : hist_u;
    int* bounds = (blockIdx.x == 0) ? bounds_m : bounds_u;
    const int t = threadIdx.x;          // 1024 threads x 64 = 64*G_SC
    const int base = t * 64;
    int v[64];
    int tot = 0;
#pragma unroll
    for (int k = 0; k < 64; ++k) { v[k] = hist[base + k]; tot += v[k]; }
    __shared__ int sc[1024];
    sc[t] = tot;
    __syncthreads();
    for (int off = 1; off < 1024; off <<= 1) {
        int x = (t >= off) ? sc[t - off] : 0;
        __syncthreads();
        sc[t] += x;
        __syncthreads();
    }
    int excl = sc[t] - tot;
#pragma unroll
    for (int k = 0; k < 64; ++k) { int tmp = v[k]; hist[base + k] = excl; excl += tmp; }
    __syncthreads();
    if (t < MBK2) bounds[t] = hist[t * G_SC];
    else if (t == MBK2) bounds[MBK2] = nE;
}

// ---------------------------------------------------------------------------
// Level-1 scatter, deterministic (LDS cursors, exclusive per-bucket chunks).
__global__ void pair_scatter_kernel(const void* __restrict__ es,
                                    const void* __restrict__ ed,
                                    const int* __restrict__ flag,
                                    const int* __restrict__ hist_m,
                                    const int* __restrict__ hist_u,
                                    unsigned* __restrict__ pr_m,
                                    unsigned* __restrict__ pr_u,
                                    int nE, int cpb) {
    __shared__ int cur[2 * MBK2];
    if (threadIdx.x < MBK2)
        cur[threadIdx.x] = hist_m[threadIdx.x * G_SC + blockIdx.x];
    else if (threadIdx.x < 2 * MBK2)
        cur[threadIdx.x] = hist_u[(threadIdx.x - MBK2) * G_SC + blockIdx.x];
    __syncthreads();
    const int is64 = *flag;
    const int e0 = blockIdx.x * cpb;
    const int e1 = min(nE, e0 + cpb);
    for (int e = e0 + threadIdx.x; e < e1; e += blockDim.x) {
        const int s = load_idx(es, e, is64);
        const int d = load_idx(ed, e, is64);
        const int b0 = (unsigned)d / SP_M;
        const int b1 = (unsigned)s / SP_U;
        const int p0 = atomicAdd(&cur[b0], 1);
        pr_m[p0] = ((unsigned)(d - b0 * SP_M) << 18) | (unsigned)s;
        const int p1 = atomicAdd(&cur[MBK2 + b1], 1);
        pr_u[p1] = ((unsigned)(s - b1 * SP_U) << 17) | (unsigned)d;
    }
}

// ---------------------------------------------------------------------------
// Merged CSR build: ONE block per bucket (LDS degree hist -> LDS scan ->
// rowptr write -> adj fill into XCD-exclusive region).
__global__ __launch_bounds__(1024) void
build_csr_kernel(const unsigned* __restrict__ pr_m, const unsigned* __restrict__ pr_u,
                 const int* __restrict__ bounds_m, const int* __restrict__ bounds_u,
                 int* __restrict__ rp_m, int* __restrict__ rp_u,
                 int* __restrict__ adj_m, int* __restrict__ adj_u, int nE) {
    __shared__ int cur[SP_U];
    __shared__ int ps[1024];
    const int t = threadIdx.x;
    const int b = blockIdx.x;
    const bool mv = (b < MBK2);
    const int bb = mv ? b : b - MBK2;
    const int span  = mv ? SP_M : SP_U;
    const int shift = mv ? 18 : 17;
    const unsigned mask = (1u << shift) - 1u;
    const unsigned* pr = mv ? pr_m : pr_u;
    const int* bounds  = mv ? bounds_m : bounds_u;
    int* rp  = mv ? rp_m : rp_u;
    int* adj = mv ? adj_m : adj_u;
    const int n_tot = mv ? NM : NU;
    const int nb = bb * span;
    const int s0 = bounds[bb], s1 = bounds[bb + 1];

    for (int i = t; i < span; i += 1024) cur[i] = 0;
    __syncthreads();
    for (int i = s0 + t; i < s1; i += 1024)
        atomicAdd(&cur[pr[i] >> shift], 1);
    __syncthreads();
    int v[4];
    int loc = 0;
#pragma unroll
    for (int k = 0; k < 4; ++k) {
        const int i = t * 4 + k;
        v[k] = (i < span) ? cur[i] : 0;
        loc += v[k];
    }
    ps[t] = loc;
    __syncthreads();
    for (int off = 1; off < 1024; off <<= 1) {
        int x = (t >= off) ? ps[t - off] : 0;
        __syncthreads();
        ps[t] += x;
        __syncthreads();
    }
    int run = s0 + ps[t] - loc;
#pragma unroll
    for (int k = 0; k < 4; ++k) {
        const int i = t * 4 + k;
        if (i < span) {
            if (nb + i < n_tot) rp[nb + i] = run;
            cur[i] = run;
            run += v[k];
        }
    }
    if (bb == MBK2 - 1 && t == 0) rp[n_tot] = nE;   // sentinel
    __syncthreads();
    for (int i = s0 + t; i < s1; i += 1024) {
        const unsigned w = pr[i];
        const int slot = atomicAdd(&cur[w >> shift], 1);
        adj[slot] = (int)(w & mask);
    }
}

// ---------------------------------------------------------------------------
// bf16 mean-aggregate gather, GROUP-PER-NODE layout: 8 nodes per wave, one
// node per 8-lane group (col = lane&7 owns dims 8c..8c+7). Each group walks
// its adjacency with a 4-deep unroll -> each dwordx4 load instruction has 8
// distinct rows in flight, x4 unroll = 32 rows/wave (vs 2-4 in the old
// butterfly layout). No cross-lane reduction at all. Writes: 8 consecutive
// rows = 1KB coalesced per wave.
__global__ __launch_bounds__(256) void
gather_mean_bf16_kernel(const ushort_t* __restrict__ xsrc,
                        const int* __restrict__ rowptr,
                        const int* __restrict__ adj,
                        ushort_t* __restrict__ agg,
                        int n0, int n1) {
    const unsigned SEL_LO = 0x00003f80u;   // bf16 (1.0, 0)
    const unsigned SEL_HI = 0x3f800000u;   // bf16 (0, 1.0)
    const int lane = threadIdx.x & 63;
    const int grp  = lane >> 3;            // node group 0..7
    const int col  = lane & 7;             // uint4 column (16B)
    const int wid  = (blockIdx.x * blockDim.x + threadIdx.x) >> 6;
    const int nw   = (gridDim.x * blockDim.x) >> 6;
    for (int ib = n0 + wid * 8; ib < n1; ib += nw * 8) {
        const int i = ib + grp;
        float a[8] = {0.f, 0.f, 0.f, 0.f, 0.f, 0.f, 0.f, 0.f};
        float b[8] = {0.f, 0.f, 0.f, 0.f, 0.f, 0.f, 0.f, 0.f};
        int r0 = 0, r1 = 0;
        if (i < n1) { r0 = rowptr[i]; r1 = rowptr[i + 1]; }
        int j = r0;
        for (; j + 3 < r1; j += 4) {
            const int s0 = adj[j];
            const int s1 = adj[j + 1];
            const int s2 = adj[j + 2];
            const int s3 = adj[j + 3];
            const uint4 v0 = ((const uint4*)(xsrc + (size_t)s0 * DIM))[col];
            const uint4 v1 = ((const uint4*)(xsrc + (size_t)s1 * DIM))[col];
            const uint4 v2 = ((const uint4*)(xsrc + (size_t)s2 * DIM))[col];
            const uint4 v3 = ((const uint4*)(xsrc + (size_t)s3 * DIM))[col];
            acc8(a, v0, SEL_LO, SEL_HI);
            acc8(b, v1, SEL_LO, SEL_HI);
            acc8(a, v2, SEL_LO, SEL_HI);
            acc8(b, v3, SEL_LO, SEL_HI);
        }
        for (; j < r1; ++j) {
            const int s0 = adj[j];
            const uint4 v0 = ((const uint4*)(xsrc + (size_t)s0 * DIM))[col];
            acc8(a, v0, SEL_LO, SEL_HI);
        }
#pragma unroll
        for (int k = 0; k < 8; ++k) a[k] += b[k];
        if (i < n1) {
            const float inv = 1.0f / fmaxf((float)(r1 - r0), 1.0f);
            uint4 o;
            o.x = pack_bf2(a[0] * inv, a[1] * inv);
            o.y = pack_bf2(a[2] * inv, a[3] * inv);
            o.z = pack_bf2(a[4] * inv, a[5] * inv);
            o.w = pack_bf2(a[6] * inv, a[7] * inv);
            ((uint4*)(agg + (size_t)(i - n0) * DIM))[col] = o;
        }
    }
}

// ---------------------------------------------------------------------------
// MFMA transform (unchanged from round 13): C[64][64] = [agg|xdst] @ wt + b.
template <int RELU>
__global__ __launch_bounds__(256) void
transform_mfma_kernel(const ushort_t* __restrict__ agg,
                      const ushort_t* __restrict__ xdst_b,
                      const ushort_t* __restrict__ wt,
                      const float* __restrict__ bl,
                      float* __restrict__ out_f,
                      ushort_t* __restrict__ out_b,
                      int n0, int n1) {
    __shared__ ushort_t sA[64 * 128];   // 16KB, swizzled granules
    __shared__ ushort_t sB[64 * 128];   // 16KB, swizzled granules

    const int tid = threadIdx.x;
    const int base = n0 + blockIdx.x * 64;
    {
        const uint4* w4 = (const uint4*)wt;
#pragma unroll
        for (int i = 0; i < 4; ++i) {
            const int idx = i * 256 + tid;        // 0..1023
            const int row = idx >> 4;             // n
            const int g   = idx & 15;             // granule (8 bf16)
            ((uint4*)sB)[row * 16 + (g ^ (row & 15))] = w4[idx];
        }
    }
#pragma unroll
    for (int i = 0; i < 4; ++i) {
        const int idx = i * 256 + tid;
        const int ln   = idx >> 4;                // node local 0..63
        const int g    = idx & 15;                // granule: 0-7 agg, 8-15 xdst
        const int node = base + ln;
        uint4 v = make_uint4(0, 0, 0, 0);
        if (node < n1)
            v = (g < 8) ? ((const uint4*)(agg + (size_t)(node - n0) * DIM))[g]
                        : ((const uint4*)(xdst_b + (size_t)node * DIM))[g - 8];
        ((uint4*)sA)[ln * 16 + (g ^ (ln & 15))] = v;
    }
    __syncthreads();

    const int w    = tid >> 6;       // wave 0..3 -> node rows w*16..+15
    const int lane = tid & 63;
    const int m    = lane & 15;
    const int kg   = lane >> 4;      // k-group (8 bf16 each)
    f32x4 acc0 = {0.f, 0.f, 0.f, 0.f}, acc1 = acc0, acc2 = acc0, acc3 = acc0;
    const int ar = w * 16 + m;       // A row
#pragma unroll
    for (int kk = 0; kk < 4; ++kk) {
        const int g = kk * 4 + kg;   // granule index of this fragment's 8 k
        const bf16x8 afr = ((const bf16x8*)sA)[ar * 16 + (g ^ (ar & 15))];
        {
            const int br = m;
            const bf16x8 bfr = ((const bf16x8*)sB)[br * 16 + (g ^ (br & 15))];
            acc0 = __builtin_amdgcn_mfma_f32_16x16x32_bf16(afr, bfr, acc0, 0, 0, 0);
        }
        {
            const int br = 16 + m;
            const bf16x8 bfr = ((const bf16x8*)sB)[br * 16 + (g ^ (br & 15))];
            acc1 = __builtin_amdgcn_mfma_f32_16x16x32_bf16(afr, bfr, acc1, 0, 0, 0);
        }
        {
            const int br = 32 + m;
            const bf16x8 bfr = ((const bf16x8*)sB)[br * 16 + (g ^ (br & 15))];
            acc2 = __builtin_amdgcn_mfma_f32_16x16x32_bf16(afr, bfr, acc2, 0, 0, 0);
        }
        {
            const int br = 48 + m;
            const bf16x8 bfr = ((const bf16x8*)sB)[br * 16 + (g ^ (br & 15))];
            acc3 = __builtin_amdgcn_mfma_f32_16x16x32_bf16(afr, bfr, acc3, 0, 0, 0);
        }
    }
    const int col = lane & 15;
    const int rb  = (lane >> 4) * 4;
    f32x4 av[4] = {acc0, acc1, acc2, acc3};
#pragma unroll
    for (int ni = 0; ni < 4; ++ni) {
        const int n = ni * 16 + col;
        const float bias = bl[n];
#pragma unroll
        for (int r = 0; r < 4; ++r) {
            const int node = base + w * 16 + rb + r;
            if (node < n1) {
                float v = av[ni][r] + bias;
                if (RELU) v = fmaxf(v, 0.f);
                if (out_f) out_f[(size_t)node * DIM + n] = v;
                if (out_b) out_b[(size_t)node * DIM + n] = pack_bf1(v);
            }
        }
    }
}

// ---------------------------------------------------------------------------
extern "C" void kernel_launch(void* const* d_in, const int* in_sizes, int n_in,
                              void* d_out, int out_size, void* d_ws, size_t ws_size,
                              hipStream_t stream) {
    const float* x_user  = (const float*)d_in[0];
    const float* x_movie = (const float*)d_in[1];
    const void*  e_src   = d_in[2];
    const void*  e_dst   = d_in[3];
    const float* W1_um_l = (const float*)d_in[4];
    const float* W1_um_r = (const float*)d_in[5];
    const float* W1_mu_l = (const float*)d_in[6];
    const float* W1_mu_r = (const float*)d_in[7];
    const float* W2_um_l = (const float*)d_in[8];
    const float* W2_um_r = (const float*)d_in[9];
    const float* W2_mu_l = (const float*)d_in[10];
    const float* W2_mu_r = (const float*)d_in[11];
    const float* b1_um = (const float*)d_in[12];
    const float* b1_mu = (const float*)d_in[13];
    const float* b2_um = (const float*)d_in[14];
    const float* b2_mu = (const float*)d_in[15];
    const int nE = in_sizes[2];
    const int cpb = (nE + G_SC - 1) / G_SC;

    auto al = [](size_t b) { return (b + 255) & ~(size_t)255; };
    const size_t fixed_b = al(4) + al(((size_t)NU + 1) * 4) + al(((size_t)NM + 1) * 4)
                         + 2 * al((size_t)MBK2 * G_SC * 4) + 2 * al((MBK2 + 1) * 4)
                         + 2 * al((size_t)nE * 4) + al(4 * 8192 * 2);
    const size_t a1_b = al((size_t)NU * DIM * 2);
    const size_t a2_b = al((size_t)NM * DIM * 2);
    const size_t pair_b = (size_t)2 * nE * 4;
    int CHKr = 50000;
    {
        const int cand[3] = {200000, 100000, 50000};
        for (int k = 0; k < 3; ++k) {
            size_t bphase = (size_t)cand[k] * DIM * 2 + (size_t)NM * DIM * 2 + 1024;
            size_t need = fixed_b + a1_b + a2_b +
                          al(bphase > pair_b ? bphase : pair_b) + 4096;
            if (need <= ws_size) { CHKr = cand[k]; break; }
        }
    }

    char* ws = (char*)d_ws;
    size_t off = 0;
    auto carve = [&](size_t bytes) {
        void* p = ws + off;
        off += al(bytes);
        return p;
    };
    int*      flag     = (int*)carve(4);
    int*      rp_u     = (int*)carve(((size_t)NU + 1) * 4);
    int*      rp_m     = (int*)carve(((size_t)NM + 1) * 4);
    int*      hist_m   = (int*)carve((size_t)MBK2 * G_SC * 4);
    int*      hist_u   = (int*)carve((size_t)MBK2 * G_SC * 4);
    int*      bounds_m = (int*)carve((MBK2 + 1) * 4);
    int*      bounds_u = (int*)carve((MBK2 + 1) * 4);
    int*      adj_u    = (int*)carve((size_t)nE * 4);
    int*      adj_m    = (int*)carve((size_t)nE * 4);
    ushort_t* wt_all   = (ushort_t*)carve(4 * 8192 * 2);    // 4 x [64][128] bf16
    ushort_t* A1 = (ushort_t*)carve((size_t)NU * DIM * 2);  // xu_bf then u1_bf
    ushort_t* A2 = (ushort_t*)carve((size_t)NM * DIM * 2);  // m1_bf
    size_t bphase = (size_t)CHKr * DIM * 2 + (size_t)NM * DIM * 2 + 1024;
    char*     B      = (char*)carve(bphase > pair_b ? bphase : pair_b);
    unsigned* pr_m   = (unsigned*)B;                        // phase A
    unsigned* pr_u   = (unsigned*)(B + (size_t)nE * 4);     // phase A
    ushort_t* agg_bf = (ushort_t*)B;                        // phase B
    ushort_t* xm_bf  = (ushort_t*)(B + al((size_t)CHKr * DIM * 2)); // phase B
    ushort_t* xu_bf  = A1;
    ushort_t* u1_bf  = A1;
    ushort_t* m1_bf  = A2;
    ushort_t* wt1m = wt_all;            // layer1 movie (W1_um)
    ushort_t* wt1u = wt_all + 8192;     // layer1 user  (W1_mu)
    ushort_t* wt2m = wt_all + 16384;    // layer2 movie (W2_um)
    ushort_t* wt2u = wt_all + 24576;    // layer2 user  (W2_mu)

    float* u2 = (float*)d_out;                    // [NU,64]
    float* m2 = (float*)d_out + (size_t)NU * DIM; // [NM,64]

    // ---- build CSR (both directions): radix binning, zero global atomics ----
    detect_idx_kernel<<<1, 256, 0, stream>>>((const unsigned int*)e_src, flag);
    count_kernel<<<G_SC, 256, 0, stream>>>(e_src, e_dst, flag,
                                           hist_m, hist_u, nE, cpb);
    hist_scan_kernel<<<2, 1024, 0, stream>>>(hist_m, hist_u,
                                             bounds_m, bounds_u, nE);
    pair_scatter_kernel<<<G_SC, 256, 0, stream>>>(e_src, e_dst, flag,
                                                  hist_m, hist_u, pr_m, pr_u,
                                                  nE, cpb);
    build_csr_kernel<<<2 * MBK2, 1024, 0, stream>>>(pr_m, pr_u,
                                                    bounds_m, bounds_u,
                                                    rp_m, rp_u, adj_m, adj_u, nE);
    // pr_m/pr_u dead from here; B switches to agg_bf/xm_bf.

    // ---- bf16 sources + transposed bf16 weights ----
    conv_bf16_kernel<<<2048, 256, 0, stream>>>((const float4*)x_user,
                                               (const float4*)x_movie,
                                               (uint2*)xu_bf, (uint2*)xm_bf);
    prep_w_kernel<<<128, 256, 0, stream>>>(W1_um_l, W1_um_r, W1_mu_l, W1_mu_r,
                                           W2_um_l, W2_um_r, W2_mu_l, W2_mu_r,
                                           wt_all);

    auto run_dir = [&](const ushort_t* src_bf, const int* rp, const int* adj,
                       const ushort_t* xdst_bf, const ushort_t* wt,
                       const float* bl, float* outf, ushort_t* outb,
                       int n_tot, int relu) {
        for (int n0 = 0; n0 < n_tot; n0 += CHKr) {
            const int n1 = min(n_tot, n0 + CHKr);
            const int gb = (n1 - n0 + 31) / 32;     // 8 nodes/wave, 4 waves/blk
            const int tb = (n1 - n0 + 63) / 64;
            gather_mean_bf16_kernel<<<gb, 256, 0, stream>>>(src_bf, rp, adj,
                                                            agg_bf, n0, n1);
            if (relu)
                transform_mfma_kernel<1><<<tb, 256, 0, stream>>>(agg_bf, xdst_bf,
                    wt, bl, outf, outb, n0, n1);
            else
                transform_mfma_kernel<0><<<tb, 256, 0, stream>>>(agg_bf, xdst_bf,
                    wt, bl, outf, outb, n0, n1);
        }
    };

    // ---- layer 1 (bf16 intermediates only) ----
    run_dir(xu_bf, rp_m, adj_m, xm_bf, wt1m, b1_um, nullptr, m1_bf, NM, 1);
    run_dir(xm_bf, rp_u, adj_u, xu_bf, wt1u, b1_mu, nullptr, u1_bf, NU, 1);
    // ---- layer 2 (fp32 outputs straight to d_out) ----
    run_dir(u1_bf, rp_m, adj_m, m1_bf, wt2m, b2_um, m2, nullptr, NM, 0);
    run_dir(m1_bf, rp_u, adj_u, u1_bf, wt2u, b2_mu, u2, nullptr, NU, 0);
}